// Round 7
// baseline (171.691 us; speedup 1.0000x reference)
//
#include <hip/hip_runtime.h>
#include <hip/hip_bf16.h>
#include <math.h>

// Problem sizes (fixed by reference)
static constexpr int Bn = 16, Sn = 512, Wn = 8, Dn = 768;
static constexpr int Mn_ = 2, WMn = 64;
static constexpr int Un = 32, WUn = 16;

#define INF_VAL 1e12f
#define INV_SQRT_D 0.03608439182435161f

// Output float offsets
static constexpr size_t OFF_GCN   = 0;                    // [16,512,768]
static constexpr size_t OFF_MASK  = 6291456;              // [16,512,1]
static constexpr size_t OFF_DENSE = 6299648;              // [16,512,512]
static constexpr size_t OFF_ADJ   = 10493952;             // [16,512,512]
static constexpr size_t OFF_MAIN  = 14688256;             // [16,2,768]
static constexpr size_t OFF_USER  = 14712832;             // [16,768]

// Workspace byte offsets (~52 MB total; ws is ~393 MB)
static constexpr size_t WSB_GBF     = 0;          // bf16 [8192][768]
static constexpr size_t WSB_GT      = 12582912;   // bf16 [16][768][512]
static constexpr size_t WSB_DENSEBF = 25165824;   // bf16 [8192][512]
static constexpr size_t WSB_HBF     = 33554432;   // bf16 [8192][768]
static constexpr size_t WSB_KWT     = 46137344;   // bf16 [768][768]  (K_w^T)
static constexpr size_t WSB_QWT     = 47316992;   // bf16 [768][768]  (Q_w^T)
static constexpr size_t WSB_MT      = 48496640;   // bf16 [768][768]  (M^T: [j][i]=M[i][j])
static constexpr size_t WSB_PARTU   = 49676288;   // f32 [512][768]
static constexpr size_t WSB_PARTM   = 51249152;   // f32 [128][768]
static constexpr size_t WSB_KBAR    = 51642368;   // f64 [768]
static constexpr size_t WSB_QBAR    = 51648512;   // f64 [768]
static constexpr size_t WSB_U       = 51654656;   // f64 [768]
static constexpr size_t WSB_V       = 51660800;   // f64 [768]
static constexpr size_t WSB_VA      = 51666944;   // f64 [768]
static constexpr size_t WSB_VB      = 51673088;   // f64 [768]
static constexpr size_t WSB_CONSTS  = 51679232;   // f64 [4]: c0,c1,c2,c3
static constexpr size_t WSB_QS      = 51679296;   // f32 [8192]
static constexpr size_t WSB_KQ      = 51712064;   // f32 [8192]
static constexpr size_t WSB_GA      = 51744832;   // f32 [8192]
static constexpr size_t WSB_GB      = 51777600;   // f32 [8192]
static constexpr size_t WSB_COLSUM  = 51810368;   // f32 [8192]
static constexpr size_t WSB_FLAGS   = 51843136;   // int [8192]
static constexpr size_t WSB_ROWSUM  = 51875904;   // f32 [8192]
static constexpr size_t WSB_UVU     = 51908672;   // f64 [8][768]
static constexpr size_t WSB_UVV     = 51957824;   // f64 [8][768]
static constexpr size_t WSB_UVA     = 52006976;   // f64 [8][768]
static constexpr size_t WSB_UVB     = 52056128;   // f64 [8][768]

typedef __attribute__((ext_vector_type(8))) short short8;
typedef __attribute__((ext_vector_type(4))) float f32x4;

static __device__ __forceinline__ ushort f2bf(float f) {
    union { float f; unsigned u; } v; v.f = f;
    unsigned u = v.u;
    unsigned r = (u + 0x7FFFu + ((u >> 16) & 1u)) >> 16;
    return (ushort)r;
}

static __device__ __forceinline__ void gload16(const void* g, void* lds) {
    __builtin_amdgcn_global_load_lds(
        (const __attribute__((address_space(1))) void*)g,
        (__attribute__((address_space(3))) void*)lds, 16, 0, 0);
}

static __device__ __forceinline__ void fmax4(float4& a, const float4& x) {
    a.x = fmaxf(a.x, x.x); a.y = fmaxf(a.y, x.y);
    a.z = fmaxf(a.z, x.z); a.w = fmaxf(a.w, x.w);
}

// ---------------------------------------------------------------------------
// fold1: blocks 0..191 kbar/qbar row sums; 192..1343 transpose-convert
// K_w->KwbT, Q_w->QwbT (bf16, [i][e]); 1344 colsum zero.
__global__ __launch_bounds__(256)
void fold1(const float* __restrict__ K_w, const float* __restrict__ K_b,
           const float* __restrict__ Q_w, const float* __restrict__ Q_b,
           double* __restrict__ kbar, double* __restrict__ qbar,
           ushort* __restrict__ KwbT, ushort* __restrict__ QwbT,
           float* __restrict__ colsum) {
    int blk = blockIdx.x, t = threadIdx.x;
    if (blk < 192) {
        int wv = t >> 6, lane = t & 63;
        int r = blk * 4 + wv;
        double sk = 0.0, sq = 0.0;
        for (int d = lane; d < Dn; d += 64) {
            sk += (double)K_w[(size_t)r * Dn + d];
            sq += (double)Q_w[(size_t)r * Dn + d];
        }
        #pragma unroll
        for (int off = 32; off > 0; off >>= 1) {
            sk += __shfl_down(sk, off, 64);
            sq += __shfl_down(sq, off, 64);
        }
        if (lane == 0) {
            kbar[r] = -1e12 * sk + (double)K_b[r];
            qbar[r] = -1e12 * sq + (double)Q_b[r];
        }
    } else if (blk < 1344) {
        int tt = blk - 192;                         // 0..1151
        const float* src = (tt < 576) ? K_w : Q_w;
        ushort* dst = (tt < 576) ? KwbT : QwbT;
        int t6 = (tt < 576) ? tt : tt - 576;
        int e0 = (t6 % 24) * 32, i0 = (t6 / 24) * 32;
        __shared__ ushort tile[32][33];
        int tx = t & 31, ty = t >> 5;
        #pragma unroll
        for (int i2 = 0; i2 < 4; ++i2)
            tile[ty + i2 * 8][tx] = f2bf(src[(size_t)(e0 + ty + i2 * 8) * Dn + i0 + tx]);
        __syncthreads();
        #pragma unroll
        for (int i2 = 0; i2 < 4; ++i2)
            dst[(size_t)(i0 + ty + i2 * 8) * Dn + e0 + tx] = tile[tx][ty + i2 * 8];
    } else {
        for (int i = t; i < Bn * Sn; i += 256) colsum[i] = 0.f;
    }
}

// u_j = sum_e Kw[e,j]*qbar_e ; v_j = sum_e Qw[e,j]*kbar_e ;
// a_j = sum_e Kw[e,j]*Qb_e  ; b_j = sum_e Qw[e,j]*Kb_e   — 8-way partials
__global__ __launch_bounds__(64)
void uv_part(const float* __restrict__ K_w, const float* __restrict__ Q_w,
             const float* __restrict__ K_b, const float* __restrict__ Q_b,
             const double* __restrict__ kbar, const double* __restrict__ qbar,
             double* __restrict__ uvu, double* __restrict__ uvv,
             double* __restrict__ uva, double* __restrict__ uvb) {
    int j = blockIdx.x * 64 + threadIdx.x;
    int e0 = blockIdx.y * 96;
    double su = 0.0, sv = 0.0, sa = 0.0, sb = 0.0;
    for (int e = e0; e < e0 + 96; ++e) {
        double kw = (double)K_w[(size_t)e * Dn + j];
        double qw = (double)Q_w[(size_t)e * Dn + j];
        su += kw * qbar[e];
        sv += qw * kbar[e];
        sa += kw * (double)Q_b[e];
        sb += qw * (double)K_b[e];
    }
    uvu[(size_t)blockIdx.y * Dn + j] = su;
    uvv[(size_t)blockIdx.y * Dn + j] = sv;
    uva[(size_t)blockIdx.y * Dn + j] = sa;
    uvb[(size_t)blockIdx.y * Dn + j] = sb;
}

// blocks 0..11: reduce u/v/a/b; block 12: consts c0..c3
__global__ __launch_bounds__(64)
void uvred_consts(const double* __restrict__ uvu, const double* __restrict__ uvv,
                  const double* __restrict__ uva, const double* __restrict__ uvb,
                  const double* __restrict__ kbar, const double* __restrict__ qbar,
                  const float* __restrict__ K_b, const float* __restrict__ Q_b,
                  double* __restrict__ u, double* __restrict__ v,
                  double* __restrict__ va, double* __restrict__ vb,
                  double* __restrict__ consts) {
    int blk = blockIdx.x;
    int l = threadIdx.x;
    if (blk < 12) {
        int j = blk * 64 + l;
        double su = 0.0, sv = 0.0, sa = 0.0, sb = 0.0;
        #pragma unroll
        for (int c = 0; c < 8; ++c) {
            su += uvu[(size_t)c * Dn + j];
            sv += uvv[(size_t)c * Dn + j];
            sa += uva[(size_t)c * Dn + j];
            sb += uvb[(size_t)c * Dn + j];
        }
        u[j] = su; v[j] = sv; va[j] = sa; vb[j] = sb;
    } else {
        double c0 = 0.0, c1 = 0.0, c2 = 0.0, c3 = 0.0;
        for (int e = l; e < Dn; e += 64) {
            c0 += kbar[e] * (double)Q_b[e];
            c1 += kbar[e] * qbar[e];
            c2 += qbar[e] * (double)K_b[e];
            c3 += (double)K_b[e] * (double)Q_b[e];
        }
        #pragma unroll
        for (int off = 32; off > 0; off >>= 1) {
            c0 += __shfl_down(c0, off, 64);
            c1 += __shfl_down(c1, off, 64);
            c2 += __shfl_down(c2, off, 64);
            c3 += __shfl_down(c3, off, 64);
        }
        if (l == 0) { consts[0] = c0; consts[1] = c1; consts[2] = c2; consts[3] = c3; }
    }
}

// ---------------------------------------------------------------------------
// Fused adj softmax + rowsum + column partial sums (single read of adj).
__global__ __launch_bounds__(512)
void adjsm_colsum_kernel(const float* __restrict__ adj, float* __restrict__ adjsm,
                         float* __restrict__ colsum, float* __restrict__ rowsum) {
    int blk = blockIdx.x;
    int b = blk >> 5, rc = blk & 31;
    int t = threadIdx.x;
    const float* base = adj + ((size_t)b * Sn + rc * 16) * Sn;
    float* obase = adjsm + ((size_t)b * Sn + rc * 16) * Sn;
    const float EM1 = 0.36787944117144233f;   // exp(-1)
    const float EP1 = 2.718281828459045f;     // exp(+1)
    __shared__ float red[8];
    float colacc = 0.f;
    for (int r = 0; r < 16; ++r) {
        float a = base[(size_t)r * Sn + t];
        colacc += a;
        float s = a;
        #pragma unroll
        for (int off = 32; off > 0; off >>= 1) s += __shfl_down(s, off, 64);
        if ((t & 63) == 0) red[t >> 6] = s;
        __syncthreads();
        float n1 = red[0] + red[1] + red[2] + red[3]
                 + red[4] + red[5] + red[6] + red[7];
        float e1, e0;
        if (n1 > 0.f) { e1 = 1.f; e0 = EM1; } else { e1 = EP1; e0 = 1.f; }
        float denom = n1 * e1 + (512.f - n1) * e0;
        float inv = 1.f / denom;
        obase[(size_t)r * Sn + t] = (a == 1.f ? e1 : e0) * inv;
        if (t == 0) rowsum[(size_t)b * Sn + rc * 16 + r] = n1;
        __syncthreads();
    }
    atomicAdd(&colsum[(size_t)b * Sn + t], colacc);
}

// ---------------------------------------------------------------------------
// g pool: bf16 g + exact f64 dots (qs,kq exact masked-path; ga,gb bias terms)
__global__ __launch_bounds__(192)
void pool_g_kernel(const int* __restrict__ words, const int* __restrict__ masks,
                   const float* __restrict__ emb,
                   const double* __restrict__ u, const double* __restrict__ v,
                   const double* __restrict__ va, const double* __restrict__ vb,
                   const double* __restrict__ consts,
                   ushort* __restrict__ gbf, float* __restrict__ qs,
                   float* __restrict__ kq, float* __restrict__ ga,
                   float* __restrict__ gb, int* __restrict__ flags) {
    int bs = blockIdx.x;
    int t = threadIdx.x;
    const int* wrow = words + (size_t)bs * Wn;
    const int* mrow = masks + (size_t)bs * Wn;
    float4 acc = make_float4(-INF_VAL, -INF_VAL, -INF_VAL, -INF_VAL);
    int nm = 0;
    #pragma unroll
    for (int w = 0; w < Wn; ++w) {
        int mk = mrow[w];
        nm += (mk != 0);
        if (mk != 0) continue;
        float4 x = ((const float4*)(emb + (size_t)wrow[w] * Dn))[t];
        fmax4(acc, x);
    }
    ushort4 o;
    o.x = f2bf(acc.x); o.y = f2bf(acc.y); o.z = f2bf(acc.z); o.w = f2bf(acc.w);
    ((ushort4*)(gbf + (size_t)bs * Dn))[t] = o;
    int j = t * 4;
    double dv = v[j] * (double)acc.x + v[j+1] * (double)acc.y
              + v[j+2] * (double)acc.z + v[j+3] * (double)acc.w;
    double du = u[j] * (double)acc.x + u[j+1] * (double)acc.y
              + u[j+2] * (double)acc.z + u[j+3] * (double)acc.w;
    double da = va[j] * (double)acc.x + va[j+1] * (double)acc.y
              + va[j+2] * (double)acc.z + va[j+3] * (double)acc.w;
    double db = vb[j] * (double)acc.x + vb[j+1] * (double)acc.y
              + vb[j+2] * (double)acc.z + vb[j+3] * (double)acc.w;
    #pragma unroll
    for (int off = 32; off > 0; off >>= 1) {
        dv += __shfl_down(dv, off, 64);
        du += __shfl_down(du, off, 64);
        da += __shfl_down(da, off, 64);
        db += __shfl_down(db, off, 64);
    }
    __shared__ double rr[12];
    if ((t & 63) == 0) {
        rr[t >> 6] = dv; rr[3 + (t >> 6)] = du;
        rr[6 + (t >> 6)] = da; rr[9 + (t >> 6)] = db;
    }
    __syncthreads();
    if (t == 0) {
        qs[bs] = (float)(rr[0] + rr[1] + rr[2] + consts[0]);
        kq[bs] = (float)(rr[3] + rr[4] + rr[5] + consts[2]);
        ga[bs] = (float)(rr[6] + rr[7] + rr[8]);
        gb[bs] = (float)(rr[9] + rr[10] + rr[11]);
        flags[bs] = (nm == Wn) ? 1 : 0;
    }
}

// merged stage1: blocks 0..127 main (16-piece chunks), 128..639 user (one user)
__global__ __launch_bounds__(192)
void pool_s1(const int* __restrict__ main_idx, const int* __restrict__ mmask,
             const int* __restrict__ user_idx, const int* __restrict__ umask,
             const float* __restrict__ emb,
             float* __restrict__ partM, float* __restrict__ partU) {
    int blk = blockIdx.x;
    int t = threadIdx.x;
    const int *irow, *mrow;
    float* dst;
    if (blk < 128) {
        int bm = blk >> 2, ch = blk & 3;
        irow = main_idx + (size_t)bm * WMn + ch * 16;
        mrow = mmask + (size_t)bm * WMn + ch * 16;
        dst = partM + (size_t)blk * Dn;
    } else {
        int bu = blk - 128;
        irow = user_idx + (size_t)bu * WUn;
        mrow = umask + (size_t)bu * WUn;
        dst = partU + (size_t)bu * Dn;
    }
    float4 acc = make_float4(-INF_VAL, -INF_VAL, -INF_VAL, -INF_VAL);
    #pragma unroll
    for (int w = 0; w < 16; ++w) {
        if (mrow[w] != 0) continue;
        float4 x = ((const float4*)(emb + (size_t)irow[w] * Dn))[t];
        fmax4(acc, x);
    }
    ((float4*)dst)[t] = acc;
}

// merged stage2 + mask: blocks 0..31 main, 32..47 user, 48..90 mask
__global__ __launch_bounds__(192)
void pool_s2m(const float* __restrict__ partM, const float* __restrict__ partU,
              float* __restrict__ outM, float* __restrict__ outU,
              const float* __restrict__ rowsum, const float* __restrict__ colsum,
              float* __restrict__ maskout) {
    int blk = blockIdx.x;
    int t = threadIdx.x;
    if (blk >= 48) {
        int i = (blk - 48) * 192 + t;
        if (i < Bn * Sn)
            maskout[i] = ((rowsum[i] + colsum[i]) == 0.f) ? 1.f : 0.f;
        return;
    }
    float4 acc = make_float4(-INF_VAL, -INF_VAL, -INF_VAL, -INF_VAL);
    float* dst;
    if (blk < 32) {
        #pragma unroll
        for (int c = 0; c < 4; ++c) {
            float4 x = ((const float4*)(partM + (size_t)(blk * 4 + c) * Dn))[t];
            fmax4(acc, x);
        }
        dst = outM + (size_t)blk * Dn;
    } else {
        int b = blk - 32;
        for (int u2 = 0; u2 < Un; ++u2) {
            float4 x = ((const float4*)(partU + (size_t)(b * Un + u2) * Dn))[t];
            fmax4(acc, x);
        }
        dst = outU + (size_t)b * Dn;
    }
    if (acc.x == -INF_VAL) acc.x = 0.f;
    if (acc.y == -INF_VAL) acc.y = 0.f;
    if (acc.z == -INF_VAL) acc.z = 0.f;
    if (acc.w == -INF_VAL) acc.w = 0.f;
    ((float4*)dst)[t] = acc;
}

// transpose bf16 g -> gT[b][d][s]
__global__ __launch_bounds__(256)
void transpose_g(const ushort* __restrict__ gbf, ushort* __restrict__ gT) {
    __shared__ ushort tile[32][33];
    int b = blockIdx.z;
    int d0 = blockIdx.x * 32, s0 = blockIdx.y * 32;
    int tx = threadIdx.x & 31, ty = threadIdx.x >> 5;
    #pragma unroll
    for (int i = 0; i < 4; ++i)
        tile[ty + i * 8][tx] = gbf[((size_t)(b * Sn + s0 + ty + i * 8)) * Dn + d0 + tx];
    __syncthreads();
    #pragma unroll
    for (int i = 0; i < 4; ++i)
        gT[((size_t)(b * Dn + d0 + ty + i * 8)) * Sn + s0 + tx] = tile[tx][ty + i * 8];
}

// ---------------------------------------------------------------------------
// bf16 MFMA GEMM: C[m][n] = sum_k A[m][k]*B[n][k]
// 128x128 tile, BK=64, 256 threads = 4 waves (2x2), 16x16x32 MFMA.
template<int OUT_BF16>
__global__ __launch_bounds__(256)
void gemm_mfma(const ushort* __restrict__ A, const ushort* __restrict__ B,
               void* __restrict__ Cout,
               int Km, int lda, int ldb, int ldc,
               long long sA, long long sB, long long sC) {
    __shared__ ushort As[128 * 64];
    __shared__ ushort Bs[128 * 64];
    const ushort* Ab = A + (size_t)blockIdx.z * sA;
    const ushort* Bb = B + (size_t)blockIdx.z * sB;
    int i0 = blockIdx.y * 128, j0 = blockIdx.x * 128;
    int tid = threadIdx.x;
    int lane = tid & 63, wv = tid >> 6;
    int wr = wv >> 1, wc = wv & 1;
    int ln15 = lane & 15, lkg = lane >> 4;
    int sub = lane >> 3;
    int c8  = lane & 7;

    f32x4 acc[4][4] = {};

    for (int k0 = 0; k0 < Km; k0 += 64) {
        #pragma unroll
        for (int it = 0; it < 4; ++it) {
            int r = it * 32 + wv * 8 + sub;
            int cc = c8 ^ (r & 7);
            ushort* dstA = As + (it * 4096 + wv * 1024) / 2;
            ushort* dstB = Bs + (it * 4096 + wv * 1024) / 2;
            gload16(Ab + (size_t)(i0 + r) * lda + k0 + cc * 8, dstA);
            gload16(Bb + (size_t)(j0 + r) * ldb + k0 + cc * 8, dstB);
        }
        __syncthreads();
        #pragma unroll
        for (int kh = 0; kh < 2; ++kh) {
            short8 af[4], bfr[4];
            int kc = kh * 4 + lkg;
            #pragma unroll
            for (int f = 0; f < 4; ++f) {
                int ra = wr * 64 + f * 16 + ln15;
                af[f] = *(const short8*)((const char*)As + ra * 128 + ((kc ^ (ra & 7)) << 4));
                int rb = wc * 64 + f * 16 + ln15;
                bfr[f] = *(const short8*)((const char*)Bs + rb * 128 + ((kc ^ (rb & 7)) << 4));
            }
            #pragma unroll
            for (int fa = 0; fa < 4; ++fa)
                #pragma unroll
                for (int fb = 0; fb < 4; ++fb)
                    acc[fa][fb] = __builtin_amdgcn_mfma_f32_16x16x32_bf16(
                        af[fa], bfr[fb], acc[fa][fb], 0, 0, 0);
        }
        __syncthreads();
    }

    #pragma unroll
    for (int fa = 0; fa < 4; ++fa) {
        #pragma unroll
        for (int fb = 0; fb < 4; ++fb) {
            int n = j0 + wc * 64 + fb * 16 + ln15;
            #pragma unroll
            for (int rr = 0; rr < 4; ++rr) {
                int m = i0 + wr * 64 + fa * 16 + lkg * 4 + rr;
                float val = acc[fa][fb][rr];
                if (OUT_BF16) {
                    ((ushort*)Cout)[(size_t)blockIdx.z * sC + (size_t)m * ldc + n] = f2bf(val);
                } else {
                    ((float*)Cout)[(size_t)blockIdx.z * sC + (size_t)m * ldc + n] = val;
                }
            }
        }
    }
}

// ---------------------------------------------------------------------------
// scores fixup + bias-rank1 correction + row softmax.
__global__ __launch_bounds__(256)
void softmax_fix(float* __restrict__ dense, const int* __restrict__ flags,
                 const float* __restrict__ qs, const float* __restrict__ kq,
                 const float* __restrict__ ga, const float* __restrict__ gb,
                 const double* __restrict__ consts, ushort* __restrict__ densebf) {
    int bs = blockIdx.x;
    int b = bs >> 9;
    int t = threadIdx.x;
    float* row = dense + (size_t)bs * 512;
    int f0 = flags[(b << 9) + t];
    int f1 = flags[(b << 9) + t + 256];
    bool sm = flags[bs] != 0;
    float x0, x1;
    if (sm) {
        float c1i = (float)consts[1] * INV_SQRT_D;
        x0 = f0 ? c1i : qs[(b << 9) + t] * INV_SQRT_D;
        x1 = f1 ? c1i : qs[(b << 9) + t + 256] * INV_SQRT_D;
    } else {
        float kqi = kq[bs] * INV_SQRT_D;
        float corr = ga[bs] + (float)consts[3];
        x0 = f0 ? kqi : (row[t] + corr + gb[(b << 9) + t]) * INV_SQRT_D;
        x1 = f1 ? kqi : (row[t + 256] + corr + gb[(b << 9) + t + 256]) * INV_SQRT_D;
    }
    float m = fmaxf(x0, x1);
    #pragma unroll
    for (int off = 32; off > 0; off >>= 1) m = fmaxf(m, __shfl_down(m, off, 64));
    __shared__ float red[4];
    __shared__ float bmax, bsum;
    if ((t & 63) == 0) red[t >> 6] = m;
    __syncthreads();
    if (t == 0) bmax = fmaxf(fmaxf(red[0], red[1]), fmaxf(red[2], red[3]));
    __syncthreads();
    float mx = bmax;
    float e0 = expf(x0 - mx), e1 = expf(x1 - mx);
    float s = e0 + e1;
    #pragma unroll
    for (int off = 32; off > 0; off >>= 1) s += __shfl_down(s, off, 64);
    if ((t & 63) == 0) red[t >> 6] = s;
    __syncthreads();
    if (t == 0) bsum = red[0] + red[1] + red[2] + red[3];
    __syncthreads();
    float inv = 1.f / bsum;
    float p0 = e0 * inv, p1 = e1 * inv;
    row[t] = p0; row[t + 256] = p1;
    ushort* bro = densebf + (size_t)bs * 512;
    bro[t] = f2bf(p0); bro[t + 256] = f2bf(p1);
}

// ---------------------------------------------------------------------------
extern "C" void kernel_launch(void* const* d_in, const int* in_sizes, int n_in,
                              void* d_out, int out_size, void* d_ws, size_t ws_size,
                              hipStream_t stream) {
    const int*   words     = (const int*)d_in[0];
    const int*   masks     = (const int*)d_in[1];
    const int*   main_idx  = (const int*)d_in[2];
    const int*   main_mask = (const int*)d_in[3];
    const int*   user_idx  = (const int*)d_in[4];
    const int*   user_mask = (const int*)d_in[5];
    const float* adj       = (const float*)d_in[6];
    const float* emb       = (const float*)d_in[7];
    const float* K_w       = (const float*)d_in[8];
    const float* K_b       = (const float*)d_in[9];
    const float* Q_w       = (const float*)d_in[10];
    const float* Q_b       = (const float*)d_in[11];

    float* out = (float*)d_out;
    char*  ws8 = (char*)d_ws;

    ushort* gbf     = (ushort*)(ws8 + WSB_GBF);
    ushort* gT      = (ushort*)(ws8 + WSB_GT);
    ushort* densebf = (ushort*)(ws8 + WSB_DENSEBF);
    ushort* hbf     = (ushort*)(ws8 + WSB_HBF);
    ushort* KwbT    = (ushort*)(ws8 + WSB_KWT);
    ushort* QwbT    = (ushort*)(ws8 + WSB_QWT);
    ushort* Mt      = (ushort*)(ws8 + WSB_MT);
    float*  partU   = (float*)(ws8 + WSB_PARTU);
    float*  partM   = (float*)(ws8 + WSB_PARTM);
    double* kbar    = (double*)(ws8 + WSB_KBAR);
    double* qbar    = (double*)(ws8 + WSB_QBAR);
    double* u       = (double*)(ws8 + WSB_U);
    double* v       = (double*)(ws8 + WSB_V);
    double* va      = (double*)(ws8 + WSB_VA);
    double* vb      = (double*)(ws8 + WSB_VB);
    double* consts  = (double*)(ws8 + WSB_CONSTS);
    float*  qs      = (float*)(ws8 + WSB_QS);
    float*  kq      = (float*)(ws8 + WSB_KQ);
    float*  ga      = (float*)(ws8 + WSB_GA);
    float*  gb      = (float*)(ws8 + WSB_GB);
    float*  colsum  = (float*)(ws8 + WSB_COLSUM);
    int*    flags   = (int*)(ws8 + WSB_FLAGS);
    float*  rowsum  = (float*)(ws8 + WSB_ROWSUM);
    double* uvu     = (double*)(ws8 + WSB_UVU);
    double* uvv     = (double*)(ws8 + WSB_UVV);
    double* uva     = (double*)(ws8 + WSB_UVA);
    double* uvb     = (double*)(ws8 + WSB_UVB);

    float* dense = out + OFF_DENSE;

    // 1-3: weight folds + transposed bf16 converts
    fold1<<<1345, 256, 0, stream>>>(K_w, K_b, Q_w, Q_b, kbar, qbar, KwbT, QwbT, colsum);
    uv_part<<<dim3(Dn / 64, 8), 64, 0, stream>>>(K_w, Q_w, K_b, Q_b, kbar, qbar,
                                                 uvu, uvv, uva, uvb);
    uvred_consts<<<13, 64, 0, stream>>>(uvu, uvv, uva, uvb, kbar, qbar, K_b, Q_b,
                                        u, v, va, vb, consts);

    // 4: Mt[j][i] = M[i][j] = sum_e Kw[e,i]Qw[e,j]  (weight Gram matrix)
    gemm_mfma<1><<<dim3(6, 6, 1), 256, 0, stream>>>(
        QwbT, KwbT, Mt, Dn, Dn, Dn, Dn, 0, 0, 0);

    // 5: adjacency softmax + rowsum + colsum (single adj read), direct to output
    adjsm_colsum_kernel<<<Bn * 32, 512, 0, stream>>>(adj, out + OFF_ADJ, colsum, rowsum);

    // 6-8: pools (+ node mask fused into stage2)
    pool_g_kernel<<<Bn * Sn, 192, 0, stream>>>(words, masks, emb, u, v, va, vb, consts,
                                               gbf, qs, kq, ga, gb, flags);
    pool_s1<<<640, 192, 0, stream>>>(main_idx, main_mask, user_idx, user_mask,
                                     emb, partM, partU);
    pool_s2m<<<91, 192, 0, stream>>>(partM, partU, out + OFF_MAIN, out + OFF_USER,
                                     rowsum, colsum, out + OFF_MASK);

    // 9: transpose g for the PV GEMM
    transpose_g<<<dim3(Dn / 32, Sn / 32, Bn), 256, 0, stream>>>(gbf, gT);

    // 10: h = g @ M  (h[s][j] = sum_i g[s,i] * Mt[j][i])
    gemm_mfma<1><<<dim3(6, 64, 1), 256, 0, stream>>>(
        gbf, Mt, hbf, Dn, Dn, Dn, Dn, 0, 0, 0);

    // 11: raw scores[b] = h[b] @ g[b]^T
    gemm_mfma<0><<<dim3(4, 4, Bn), 256, 0, stream>>>(
        hbf, gbf, dense, Dn, Dn, Dn, Sn,
        (long long)Sn * Dn, (long long)Sn * Dn, (long long)Sn * Sn);

    // 12: fixup masked rows/cols + bias rank-1 + softmax; f32 dense + bf16 copy
    softmax_fix<<<Bn * Sn, 256, 0, stream>>>(dense, flags, qs, kq, ga, gb, consts, densebf);

    // 13: gcn[b] = P[b] @ g[b]
    gemm_mfma<0><<<dim3(6, 4, Bn), 256, 0, stream>>>(
        densebf, gT, out + OFF_GCN, Sn, Sn, Sn, Dn,
        (long long)Sn * Sn, (long long)Dn * Sn, (long long)Sn * Dn);
}

// Round 8
// 164.941 us; speedup vs baseline: 1.0409x; 1.0409x over previous
//
#include <hip/hip_runtime.h>
#include <hip/hip_bf16.h>
#include <math.h>

// Problem sizes (fixed by reference)
static constexpr int Bn = 16, Sn = 512, Wn = 8, Dn = 768;
static constexpr int Mn_ = 2, WMn = 64;
static constexpr int Un = 32, WUn = 16;

#define INF_VAL 1e12f
#define INV_SQRT_D 0.03608439182435161f

// Output float offsets
static constexpr size_t OFF_GCN   = 0;                    // [16,512,768]
static constexpr size_t OFF_MASK  = 6291456;              // [16,512,1]
static constexpr size_t OFF_DENSE = 6299648;              // [16,512,512]
static constexpr size_t OFF_ADJ   = 10493952;             // [16,512,512]
static constexpr size_t OFF_MAIN  = 14688256;             // [16,2,768]
static constexpr size_t OFF_USER  = 14712832;             // [16,768]

// Workspace byte offsets (~52 MB total; ws is ~393 MB)
static constexpr size_t WSB_GBF     = 0;          // bf16 [8192][768]
static constexpr size_t WSB_GT      = 12582912;   // bf16 [16][768][512]
static constexpr size_t WSB_DENSEBF = 25165824;   // bf16 [8192][512]
static constexpr size_t WSB_HBF     = 33554432;   // bf16 [8192][768]
static constexpr size_t WSB_KWT     = 46137344;   // bf16 [768][768]  (K_w^T)
static constexpr size_t WSB_QWT     = 47316992;   // bf16 [768][768]  (Q_w^T)
static constexpr size_t WSB_MT      = 48496640;   // bf16 [768][768]  (M^T: [j][i]=M[i][j])
static constexpr size_t WSB_PARTU   = 49676288;   // f32 [512][768]
static constexpr size_t WSB_PARTM   = 51249152;   // f32 [128][768]
static constexpr size_t WSB_KBAR    = 51642368;   // f64 [768]
static constexpr size_t WSB_QBAR    = 51648512;   // f64 [768]
static constexpr size_t WSB_U       = 51654656;   // f64 [768]
static constexpr size_t WSB_V       = 51660800;   // f64 [768]
static constexpr size_t WSB_VA      = 51666944;   // f64 [768]
static constexpr size_t WSB_VB      = 51673088;   // f64 [768]
static constexpr size_t WSB_CONSTS  = 51679232;   // f64 [4]: c0,c1,c2,c3
static constexpr size_t WSB_QS      = 51679296;   // f32 [8192]
static constexpr size_t WSB_KQ      = 51712064;   // f32 [8192]
static constexpr size_t WSB_GA      = 51744832;   // f32 [8192]
static constexpr size_t WSB_GB      = 51777600;   // f32 [8192]
static constexpr size_t WSB_COLSUM  = 51810368;   // f32 [8192]
static constexpr size_t WSB_FLAGS   = 51843136;   // int [8192]
static constexpr size_t WSB_ROWSUM  = 51875904;   // f32 [8192]
static constexpr size_t WSB_UVU     = 51908672;   // f64 [8][768]
static constexpr size_t WSB_UVV     = 51957824;   // f64 [8][768]
static constexpr size_t WSB_UVA     = 52006976;   // f64 [8][768]
static constexpr size_t WSB_UVB     = 52056128;   // f64 [8][768]

typedef __attribute__((ext_vector_type(8))) short short8;
typedef __attribute__((ext_vector_type(4))) float f32x4;

static __device__ __forceinline__ ushort f2bf(float f) {
    union { float f; unsigned u; } v; v.f = f;
    unsigned u = v.u;
    unsigned r = (u + 0x7FFFu + ((u >> 16) & 1u)) >> 16;
    return (ushort)r;
}

static __device__ __forceinline__ void gload16(const void* g, void* lds) {
    __builtin_amdgcn_global_load_lds(
        (const __attribute__((address_space(1))) void*)g,
        (__attribute__((address_space(3))) void*)lds, 16, 0, 0);
}

static __device__ __forceinline__ void fmax4(float4& a, const float4& x) {
    a.x = fmaxf(a.x, x.x); a.y = fmaxf(a.y, x.y);
    a.z = fmaxf(a.z, x.z); a.w = fmaxf(a.w, x.w);
}

// ---------------------------------------------------------------------------
// fold1: blocks 0..191 kbar/qbar row sums; 192..1343 transpose-convert
// K_w->KwbT, Q_w->QwbT (bf16, [i][e]); 1344 colsum zero.
__global__ __launch_bounds__(256)
void fold1(const float* __restrict__ K_w, const float* __restrict__ K_b,
           const float* __restrict__ Q_w, const float* __restrict__ Q_b,
           double* __restrict__ kbar, double* __restrict__ qbar,
           ushort* __restrict__ KwbT, ushort* __restrict__ QwbT,
           float* __restrict__ colsum) {
    int blk = blockIdx.x, t = threadIdx.x;
    if (blk < 192) {
        int wv = t >> 6, lane = t & 63;
        int r = blk * 4 + wv;
        double sk = 0.0, sq = 0.0;
        for (int d = lane; d < Dn; d += 64) {
            sk += (double)K_w[(size_t)r * Dn + d];
            sq += (double)Q_w[(size_t)r * Dn + d];
        }
        #pragma unroll
        for (int off = 32; off > 0; off >>= 1) {
            sk += __shfl_down(sk, off, 64);
            sq += __shfl_down(sq, off, 64);
        }
        if (lane == 0) {
            kbar[r] = -1e12 * sk + (double)K_b[r];
            qbar[r] = -1e12 * sq + (double)Q_b[r];
        }
    } else if (blk < 1344) {
        int tt = blk - 192;                         // 0..1151
        const float* src = (tt < 576) ? K_w : Q_w;
        ushort* dst = (tt < 576) ? KwbT : QwbT;
        int t6 = (tt < 576) ? tt : tt - 576;
        int e0 = (t6 % 24) * 32, i0 = (t6 / 24) * 32;
        __shared__ ushort tile[32][33];
        int tx = t & 31, ty = t >> 5;
        #pragma unroll
        for (int i2 = 0; i2 < 4; ++i2)
            tile[ty + i2 * 8][tx] = f2bf(src[(size_t)(e0 + ty + i2 * 8) * Dn + i0 + tx]);
        __syncthreads();
        #pragma unroll
        for (int i2 = 0; i2 < 4; ++i2)
            dst[(size_t)(i0 + ty + i2 * 8) * Dn + e0 + tx] = tile[tx][ty + i2 * 8];
    } else {
        for (int i = t; i < Bn * Sn; i += 256) colsum[i] = 0.f;
    }
}

// u/v/a/b partials (8-way over e-chunks)
__global__ __launch_bounds__(64)
void uv_part(const float* __restrict__ K_w, const float* __restrict__ Q_w,
             const float* __restrict__ K_b, const float* __restrict__ Q_b,
             const double* __restrict__ kbar, const double* __restrict__ qbar,
             double* __restrict__ uvu, double* __restrict__ uvv,
             double* __restrict__ uva, double* __restrict__ uvb) {
    int j = blockIdx.x * 64 + threadIdx.x;
    int e0 = blockIdx.y * 96;
    double su = 0.0, sv = 0.0, sa = 0.0, sb = 0.0;
    for (int e = e0; e < e0 + 96; ++e) {
        double kw = (double)K_w[(size_t)e * Dn + j];
        double qw = (double)Q_w[(size_t)e * Dn + j];
        su += kw * qbar[e];
        sv += qw * kbar[e];
        sa += kw * (double)Q_b[e];
        sb += qw * (double)K_b[e];
    }
    uvu[(size_t)blockIdx.y * Dn + j] = su;
    uvv[(size_t)blockIdx.y * Dn + j] = sv;
    uva[(size_t)blockIdx.y * Dn + j] = sa;
    uvb[(size_t)blockIdx.y * Dn + j] = sb;
}

// blocks 0..11: reduce u/v/a/b; block 12: consts c0..c3
__global__ __launch_bounds__(64)
void uvred_consts(const double* __restrict__ uvu, const double* __restrict__ uvv,
                  const double* __restrict__ uva, const double* __restrict__ uvb,
                  const double* __restrict__ kbar, const double* __restrict__ qbar,
                  const float* __restrict__ K_b, const float* __restrict__ Q_b,
                  double* __restrict__ u, double* __restrict__ v,
                  double* __restrict__ va, double* __restrict__ vb,
                  double* __restrict__ consts) {
    int blk = blockIdx.x;
    int l = threadIdx.x;
    if (blk < 12) {
        int j = blk * 64 + l;
        double su = 0.0, sv = 0.0, sa = 0.0, sb = 0.0;
        #pragma unroll
        for (int c = 0; c < 8; ++c) {
            su += uvu[(size_t)c * Dn + j];
            sv += uvv[(size_t)c * Dn + j];
            sa += uva[(size_t)c * Dn + j];
            sb += uvb[(size_t)c * Dn + j];
        }
        u[j] = su; v[j] = sv; va[j] = sa; vb[j] = sb;
    } else {
        double c0 = 0.0, c1 = 0.0, c2 = 0.0, c3 = 0.0;
        for (int e = l; e < Dn; e += 64) {
            c0 += kbar[e] * (double)Q_b[e];
            c1 += kbar[e] * qbar[e];
            c2 += qbar[e] * (double)K_b[e];
            c3 += (double)K_b[e] * (double)Q_b[e];
        }
        #pragma unroll
        for (int off = 32; off > 0; off >>= 1) {
            c0 += __shfl_down(c0, off, 64);
            c1 += __shfl_down(c1, off, 64);
            c2 += __shfl_down(c2, off, 64);
            c3 += __shfl_down(c3, off, 64);
        }
        if (l == 0) { consts[0] = c0; consts[1] = c1; consts[2] = c2; consts[3] = c3; }
    }
}

// ---------------------------------------------------------------------------
// Fused adj softmax + rowsum + column partial sums (single read of adj).
__global__ __launch_bounds__(512)
void adjsm_colsum_kernel(const float* __restrict__ adj, float* __restrict__ adjsm,
                         float* __restrict__ colsum, float* __restrict__ rowsum) {
    int blk = blockIdx.x;
    int b = blk >> 5, rc = blk & 31;
    int t = threadIdx.x;
    const float* base = adj + ((size_t)b * Sn + rc * 16) * Sn;
    float* obase = adjsm + ((size_t)b * Sn + rc * 16) * Sn;
    const float EM1 = 0.36787944117144233f;   // exp(-1)
    const float EP1 = 2.718281828459045f;     // exp(+1)
    __shared__ float red[8];
    float colacc = 0.f;
    for (int r = 0; r < 16; ++r) {
        float a = base[(size_t)r * Sn + t];
        colacc += a;
        float s = a;
        #pragma unroll
        for (int off = 32; off > 0; off >>= 1) s += __shfl_down(s, off, 64);
        if ((t & 63) == 0) red[t >> 6] = s;
        __syncthreads();
        float n1 = red[0] + red[1] + red[2] + red[3]
                 + red[4] + red[5] + red[6] + red[7];
        float e1, e0;
        if (n1 > 0.f) { e1 = 1.f; e0 = EM1; } else { e1 = EP1; e0 = 1.f; }
        float denom = n1 * e1 + (512.f - n1) * e0;
        float inv = 1.f / denom;
        obase[(size_t)r * Sn + t] = (a == 1.f ? e1 : e0) * inv;
        if (t == 0) rowsum[(size_t)b * Sn + rc * 16 + r] = n1;
        __syncthreads();
    }
    atomicAdd(&colsum[(size_t)b * Sn + t], colacc);
}

// ---------------------------------------------------------------------------
// merged: blocks 0..8191 = g pool (+f64 dots); 8192..8319 main s1; 8320..8831 user s1
__global__ __launch_bounds__(192)
void pool_g_s1(const int* __restrict__ words, const int* __restrict__ masks,
               const int* __restrict__ main_idx, const int* __restrict__ mmask,
               const int* __restrict__ user_idx, const int* __restrict__ umask,
               const float* __restrict__ emb,
               const double* __restrict__ u, const double* __restrict__ v,
               const double* __restrict__ va, const double* __restrict__ vb,
               const double* __restrict__ consts,
               ushort* __restrict__ gbf, float* __restrict__ qs,
               float* __restrict__ kq, float* __restrict__ ga,
               float* __restrict__ gb, int* __restrict__ flags,
               float* __restrict__ partM, float* __restrict__ partU) {
    int blk = blockIdx.x;
    int t = threadIdx.x;
    if (blk >= Bn * Sn) {
        // pool_s1 half: 16-piece partial max per block
        int s1 = blk - Bn * Sn;
        const int *irow, *mrow;
        float* dst;
        if (s1 < 128) {
            int bm = s1 >> 2, ch = s1 & 3;
            irow = main_idx + (size_t)bm * WMn + ch * 16;
            mrow = mmask + (size_t)bm * WMn + ch * 16;
            dst = partM + (size_t)s1 * Dn;
        } else {
            int bu = s1 - 128;
            irow = user_idx + (size_t)bu * WUn;
            mrow = umask + (size_t)bu * WUn;
            dst = partU + (size_t)bu * Dn;
        }
        float4 acc = make_float4(-INF_VAL, -INF_VAL, -INF_VAL, -INF_VAL);
        #pragma unroll
        for (int w = 0; w < 16; ++w) {
            if (mrow[w] != 0) continue;
            float4 x = ((const float4*)(emb + (size_t)irow[w] * Dn))[t];
            fmax4(acc, x);
        }
        ((float4*)dst)[t] = acc;
        return;
    }
    int bs = blk;
    const int* wrow = words + (size_t)bs * Wn;
    const int* mrow = masks + (size_t)bs * Wn;
    float4 acc = make_float4(-INF_VAL, -INF_VAL, -INF_VAL, -INF_VAL);
    int nm = 0;
    #pragma unroll
    for (int w = 0; w < Wn; ++w) {
        int mk = mrow[w];
        nm += (mk != 0);
        if (mk != 0) continue;
        float4 x = ((const float4*)(emb + (size_t)wrow[w] * Dn))[t];
        fmax4(acc, x);
    }
    ushort4 o;
    o.x = f2bf(acc.x); o.y = f2bf(acc.y); o.z = f2bf(acc.z); o.w = f2bf(acc.w);
    ((ushort4*)(gbf + (size_t)bs * Dn))[t] = o;
    int j = t * 4;
    double dv = v[j] * (double)acc.x + v[j+1] * (double)acc.y
              + v[j+2] * (double)acc.z + v[j+3] * (double)acc.w;
    double du = u[j] * (double)acc.x + u[j+1] * (double)acc.y
              + u[j+2] * (double)acc.z + u[j+3] * (double)acc.w;
    double da = va[j] * (double)acc.x + va[j+1] * (double)acc.y
              + va[j+2] * (double)acc.z + va[j+3] * (double)acc.w;
    double db = vb[j] * (double)acc.x + vb[j+1] * (double)acc.y
              + vb[j+2] * (double)acc.z + vb[j+3] * (double)acc.w;
    #pragma unroll
    for (int off = 32; off > 0; off >>= 1) {
        dv += __shfl_down(dv, off, 64);
        du += __shfl_down(du, off, 64);
        da += __shfl_down(da, off, 64);
        db += __shfl_down(db, off, 64);
    }
    __shared__ double rr[12];
    if ((t & 63) == 0) {
        rr[t >> 6] = dv; rr[3 + (t >> 6)] = du;
        rr[6 + (t >> 6)] = da; rr[9 + (t >> 6)] = db;
    }
    __syncthreads();
    if (t == 0) {
        qs[bs] = (float)(rr[0] + rr[1] + rr[2] + consts[0]);
        kq[bs] = (float)(rr[3] + rr[4] + rr[5] + consts[2]);
        ga[bs] = (float)(rr[6] + rr[7] + rr[8]);
        gb[bs] = (float)(rr[9] + rr[10] + rr[11]);
        flags[bs] = (nm == Wn) ? 1 : 0;
    }
}

// merged stage2 + mask: blocks 0..31 main, 32..47 user, 48..90 mask
__global__ __launch_bounds__(192)
void pool_s2m(const float* __restrict__ partM, const float* __restrict__ partU,
              float* __restrict__ outM, float* __restrict__ outU,
              const float* __restrict__ rowsum, const float* __restrict__ colsum,
              float* __restrict__ maskout) {
    int blk = blockIdx.x;
    int t = threadIdx.x;
    if (blk >= 48) {
        int i = (blk - 48) * 192 + t;
        if (i < Bn * Sn)
            maskout[i] = ((rowsum[i] + colsum[i]) == 0.f) ? 1.f : 0.f;
        return;
    }
    float4 acc = make_float4(-INF_VAL, -INF_VAL, -INF_VAL, -INF_VAL);
    float* dst;
    if (blk < 32) {
        #pragma unroll
        for (int c = 0; c < 4; ++c) {
            float4 x = ((const float4*)(partM + (size_t)(blk * 4 + c) * Dn))[t];
            fmax4(acc, x);
        }
        dst = outM + (size_t)blk * Dn;
    } else {
        int b = blk - 32;
        for (int u2 = 0; u2 < Un; ++u2) {
            float4 x = ((const float4*)(partU + (size_t)(b * Un + u2) * Dn))[t];
            fmax4(acc, x);
        }
        dst = outU + (size_t)b * Dn;
    }
    if (acc.x == -INF_VAL) acc.x = 0.f;
    if (acc.y == -INF_VAL) acc.y = 0.f;
    if (acc.z == -INF_VAL) acc.z = 0.f;
    if (acc.w == -INF_VAL) acc.w = 0.f;
    ((float4*)dst)[t] = acc;
}

// transpose bf16 g -> gT[b][d][s]
__global__ __launch_bounds__(256)
void transpose_g(const ushort* __restrict__ gbf, ushort* __restrict__ gT) {
    __shared__ ushort tile[32][33];
    int b = blockIdx.z;
    int d0 = blockIdx.x * 32, s0 = blockIdx.y * 32;
    int tx = threadIdx.x & 31, ty = threadIdx.x >> 5;
    #pragma unroll
    for (int i = 0; i < 4; ++i)
        tile[ty + i * 8][tx] = gbf[((size_t)(b * Sn + s0 + ty + i * 8)) * Dn + d0 + tx];
    __syncthreads();
    #pragma unroll
    for (int i = 0; i < 4; ++i)
        gT[((size_t)(b * Dn + d0 + ty + i * 8)) * Sn + s0 + tx] = tile[tx][ty + i * 8];
}

// ---------------------------------------------------------------------------
// bf16 MFMA GEMM: C[m][n] = sum_k A[m][k]*B[n][k]
// 128xBN tile (BN=128 or 64), BK=64, 256 threads = 4 waves (2x2), 16x16x32 MFMA.
// BN=64 doubles the grid for small-N GEMMs -> >=2 blocks/CU -> TLP hides K-step
// latency (these GEMMs are latency-bound at 1 block/CU, R6 post-mortem).
template<int OUT_BF16, int BN>
__global__ __launch_bounds__(256)
void gemm_mfma(const ushort* __restrict__ A, const ushort* __restrict__ B,
               void* __restrict__ Cout,
               int Km, int lda, int ldb, int ldc,
               long long sA, long long sB, long long sC) {
    constexpr int NFB = BN / 32;          // per-wave N-frags (wave spans BN/2)
    __shared__ ushort As[128 * 64];
    __shared__ ushort Bs[BN * 64];
    const ushort* Ab = A + (size_t)blockIdx.z * sA;
    const ushort* Bb = B + (size_t)blockIdx.z * sB;
    int i0 = blockIdx.y * 128, j0 = blockIdx.x * BN;
    int tid = threadIdx.x;
    int lane = tid & 63, wv = tid >> 6;
    int wr = wv >> 1, wc = wv & 1;
    int ln15 = lane & 15, lkg = lane >> 4;
    int sub = lane >> 3;
    int c8  = lane & 7;

    f32x4 acc[4][NFB] = {};

    for (int k0 = 0; k0 < Km; k0 += 64) {
        #pragma unroll
        for (int it = 0; it < 4; ++it) {
            int r = it * 32 + wv * 8 + sub;
            int cc = c8 ^ (r & 7);
            ushort* dstA = As + (it * 4096 + wv * 1024) / 2;
            gload16(Ab + (size_t)(i0 + r) * lda + k0 + cc * 8, dstA);
        }
        #pragma unroll
        for (int it = 0; it < BN / 32; ++it) {
            int r = it * 32 + wv * 8 + sub;
            int cc = c8 ^ (r & 7);
            ushort* dstB = Bs + (it * 4096 + wv * 1024) / 2;
            gload16(Bb + (size_t)(j0 + r) * ldb + k0 + cc * 8, dstB);
        }
        __syncthreads();
        #pragma unroll
        for (int kh = 0; kh < 2; ++kh) {
            short8 af[4], bfr[NFB];
            int kc = kh * 4 + lkg;
            #pragma unroll
            for (int f = 0; f < 4; ++f) {
                int ra = wr * 64 + f * 16 + ln15;
                af[f] = *(const short8*)((const char*)As + ra * 128 + ((kc ^ (ra & 7)) << 4));
            }
            #pragma unroll
            for (int f = 0; f < NFB; ++f) {
                int rb = wc * (BN / 2) + f * 16 + ln15;
                bfr[f] = *(const short8*)((const char*)Bs + rb * 128 + ((kc ^ (rb & 7)) << 4));
            }
            #pragma unroll
            for (int fa = 0; fa < 4; ++fa)
                #pragma unroll
                for (int fb = 0; fb < NFB; ++fb)
                    acc[fa][fb] = __builtin_amdgcn_mfma_f32_16x16x32_bf16(
                        af[fa], bfr[fb], acc[fa][fb], 0, 0, 0);
        }
        __syncthreads();
    }

    #pragma unroll
    for (int fa = 0; fa < 4; ++fa) {
        #pragma unroll
        for (int fb = 0; fb < NFB; ++fb) {
            int n = j0 + wc * (BN / 2) + fb * 16 + ln15;
            #pragma unroll
            for (int rr = 0; rr < 4; ++rr) {
                int m = i0 + wr * 64 + fa * 16 + lkg * 4 + rr;
                float val = acc[fa][fb][rr];
                if (OUT_BF16) {
                    ((ushort*)Cout)[(size_t)blockIdx.z * sC + (size_t)m * ldc + n] = f2bf(val);
                } else {
                    ((float*)Cout)[(size_t)blockIdx.z * sC + (size_t)m * ldc + n] = val;
                }
            }
        }
    }
}

// ---------------------------------------------------------------------------
// scores fixup + bias-rank1 correction + row softmax.
__global__ __launch_bounds__(256)
void softmax_fix(float* __restrict__ dense, const int* __restrict__ flags,
                 const float* __restrict__ qs, const float* __restrict__ kq,
                 const float* __restrict__ ga, const float* __restrict__ gb,
                 const double* __restrict__ consts, ushort* __restrict__ densebf) {
    int bs = blockIdx.x;
    int b = bs >> 9;
    int t = threadIdx.x;
    float* row = dense + (size_t)bs * 512;
    int f0 = flags[(b << 9) + t];
    int f1 = flags[(b << 9) + t + 256];
    bool sm = flags[bs] != 0;
    float x0, x1;
    if (sm) {
        float c1i = (float)consts[1] * INV_SQRT_D;
        x0 = f0 ? c1i : qs[(b << 9) + t] * INV_SQRT_D;
        x1 = f1 ? c1i : qs[(b << 9) + t + 256] * INV_SQRT_D;
    } else {
        float kqi = kq[bs] * INV_SQRT_D;
        float corr = ga[bs] + (float)consts[3];
        x0 = f0 ? kqi : (row[t] + corr + gb[(b << 9) + t]) * INV_SQRT_D;
        x1 = f1 ? kqi : (row[t + 256] + corr + gb[(b << 9) + t + 256]) * INV_SQRT_D;
    }
    float m = fmaxf(x0, x1);
    #pragma unroll
    for (int off = 32; off > 0; off >>= 1) m = fmaxf(m, __shfl_down(m, off, 64));
    __shared__ float red[4];
    __shared__ float bmax, bsum;
    if ((t & 63) == 0) red[t >> 6] = m;
    __syncthreads();
    if (t == 0) bmax = fmaxf(fmaxf(red[0], red[1]), fmaxf(red[2], red[3]));
    __syncthreads();
    float mx = bmax;
    float e0 = expf(x0 - mx), e1 = expf(x1 - mx);
    float s = e0 + e1;
    #pragma unroll
    for (int off = 32; off > 0; off >>= 1) s += __shfl_down(s, off, 64);
    if ((t & 63) == 0) red[t >> 6] = s;
    __syncthreads();
    if (t == 0) bsum = red[0] + red[1] + red[2] + red[3];
    __syncthreads();
    float inv = 1.f / bsum;
    float p0 = e0 * inv, p1 = e1 * inv;
    row[t] = p0; row[t + 256] = p1;
    ushort* bro = densebf + (size_t)bs * 512;
    bro[t] = f2bf(p0); bro[t + 256] = f2bf(p1);
}

// ---------------------------------------------------------------------------
extern "C" void kernel_launch(void* const* d_in, const int* in_sizes, int n_in,
                              void* d_out, int out_size, void* d_ws, size_t ws_size,
                              hipStream_t stream) {
    const int*   words     = (const int*)d_in[0];
    const int*   masks     = (const int*)d_in[1];
    const int*   main_idx  = (const int*)d_in[2];
    const int*   main_mask = (const int*)d_in[3];
    const int*   user_idx  = (const int*)d_in[4];
    const int*   user_mask = (const int*)d_in[5];
    const float* adj       = (const float*)d_in[6];
    const float* emb       = (const float*)d_in[7];
    const float* K_w       = (const float*)d_in[8];
    const float* K_b       = (const float*)d_in[9];
    const float* Q_w       = (const float*)d_in[10];
    const float* Q_b       = (const float*)d_in[11];

    float* out = (float*)d_out;
    char*  ws8 = (char*)d_ws;

    ushort* gbf     = (ushort*)(ws8 + WSB_GBF);
    ushort* gT      = (ushort*)(ws8 + WSB_GT);
    ushort* densebf = (ushort*)(ws8 + WSB_DENSEBF);
    ushort* hbf     = (ushort*)(ws8 + WSB_HBF);
    ushort* KwbT    = (ushort*)(ws8 + WSB_KWT);
    ushort* QwbT    = (ushort*)(ws8 + WSB_QWT);
    ushort* Mt      = (ushort*)(ws8 + WSB_MT);
    float*  partU   = (float*)(ws8 + WSB_PARTU);
    float*  partM   = (float*)(ws8 + WSB_PARTM);
    double* kbar    = (double*)(ws8 + WSB_KBAR);
    double* qbar    = (double*)(ws8 + WSB_QBAR);
    double* u       = (double*)(ws8 + WSB_U);
    double* v       = (double*)(ws8 + WSB_V);
    double* va      = (double*)(ws8 + WSB_VA);
    double* vb      = (double*)(ws8 + WSB_VB);
    double* consts  = (double*)(ws8 + WSB_CONSTS);
    float*  qs      = (float*)(ws8 + WSB_QS);
    float*  kq      = (float*)(ws8 + WSB_KQ);
    float*  ga      = (float*)(ws8 + WSB_GA);
    float*  gb      = (float*)(ws8 + WSB_GB);
    float*  colsum  = (float*)(ws8 + WSB_COLSUM);
    int*    flags   = (int*)(ws8 + WSB_FLAGS);
    float*  rowsum  = (float*)(ws8 + WSB_ROWSUM);
    double* uvu     = (double*)(ws8 + WSB_UVU);
    double* uvv     = (double*)(ws8 + WSB_UVV);
    double* uva     = (double*)(ws8 + WSB_UVA);
    double* uvb     = (double*)(ws8 + WSB_UVB);

    float* dense = out + OFF_DENSE;

    // 1: weight row-sums + transposed bf16 converts + colsum zero
    fold1<<<1345, 256, 0, stream>>>(K_w, K_b, Q_w, Q_b, kbar, qbar, KwbT, QwbT, colsum);

    // 2: Mt[j][i] = M[i][j] = sum_e Kw[e,i]Qw[e,j]  (weight Gram; BN=64 -> 72 blocks)
    gemm_mfma<1, 64><<<dim3(12, 6, 1), 256, 0, stream>>>(
        QwbT, KwbT, Mt, Dn, Dn, Dn, Dn, 0, 0, 0);

    // 3-4: u/v/a/b fold partials + reduce/consts
    uv_part<<<dim3(Dn / 64, 8), 64, 0, stream>>>(K_w, Q_w, K_b, Q_b, kbar, qbar,
                                                 uvu, uvv, uva, uvb);
    uvred_consts<<<13, 64, 0, stream>>>(uvu, uvv, uva, uvb, kbar, qbar, K_b, Q_b,
                                        u, v, va, vb, consts);

    // 5: adjacency softmax + rowsum + colsum (single adj read), direct to output
    adjsm_colsum_kernel<<<Bn * 32, 512, 0, stream>>>(adj, out + OFF_ADJ, colsum, rowsum);

    // 6-7: pools (g + s1 merged; mask fused into s2)
    pool_g_s1<<<Bn * Sn + 640, 192, 0, stream>>>(
        words, masks, main_idx, main_mask, user_idx, user_mask, emb,
        u, v, va, vb, consts, gbf, qs, kq, ga, gb, flags, partM, partU);
    pool_s2m<<<91, 192, 0, stream>>>(partM, partU, out + OFF_MAIN, out + OFF_USER,
                                     rowsum, colsum, out + OFF_MASK);

    // 8: transpose g for the PV GEMM
    transpose_g<<<dim3(Dn / 32, Sn / 32, Bn), 256, 0, stream>>>(gbf, gT);

    // 9: h = g @ M   (BN=64 -> 768 blocks, 3/CU)
    gemm_mfma<1, 64><<<dim3(12, 64, 1), 256, 0, stream>>>(
        gbf, Mt, hbf, Dn, Dn, Dn, Dn, 0, 0, 0);

    // 10: raw scores[b] = h[b] @ g[b]^T  (BN=64 -> 512 blocks, 2/CU)
    gemm_mfma<0, 64><<<dim3(8, 4, Bn), 256, 0, stream>>>(
        hbf, gbf, dense, Dn, Dn, Dn, Sn,
        (long long)Sn * Dn, (long long)Sn * Dn, (long long)Sn * Sn);

    // 11: fixup masked rows/cols + bias rank-1 + softmax; f32 dense + bf16 copy
    softmax_fix<<<Bn * Sn, 256, 0, stream>>>(dense, flags, qs, kq, ga, gb, consts, densebf);

    // 12: gcn[b] = P[b] @ g[b]  (BN=64 -> 768 blocks, 3/CU)
    gemm_mfma<0, 64><<<dim3(12, 4, Bn), 256, 0, stream>>>(
        densebf, gT, out + OFF_GCN, Sn, Sn, Sn, Dn,
        (long long)Sn * Sn, (long long)Dn * Sn, (long long)Sn * Dn);
}

// Round 9
// 157.287 us; speedup vs baseline: 1.0916x; 1.0487x over previous
//
#include <hip/hip_runtime.h>
#include <hip/hip_bf16.h>
#include <math.h>

// Problem sizes (fixed by reference)
static constexpr int Bn = 16, Sn = 512, Wn = 8, Dn = 768;
static constexpr int Mn_ = 2, WMn = 64;
static constexpr int Un = 32, WUn = 16;

#define INF_VAL 1e12f
#define INV_SQRT_D 0.03608439182435161f

// Output float offsets
static constexpr size_t OFF_GCN   = 0;                    // [16,512,768]
static constexpr size_t OFF_MASK  = 6291456;              // [16,512,1]
static constexpr size_t OFF_DENSE = 6299648;              // [16,512,512]
static constexpr size_t OFF_ADJ   = 10493952;             // [16,512,512]
static constexpr size_t OFF_MAIN  = 14688256;             // [16,2,768]
static constexpr size_t OFF_USER  = 14712832;             // [16,768]

// Workspace byte offsets (~52 MB total; ws is ~393 MB)
static constexpr size_t WSB_GBF     = 0;          // bf16 [8192][768]
static constexpr size_t WSB_GT      = 12582912;   // bf16 [16][768][512]
static constexpr size_t WSB_DENSEBF = 25165824;   // bf16 [8192][512]
static constexpr size_t WSB_HBF     = 33554432;   // bf16 [8192][768]
static constexpr size_t WSB_KWT     = 46137344;   // bf16 [768][768]  (K_w^T)
static constexpr size_t WSB_QWT     = 47316992;   // bf16 [768][768]  (Q_w^T)
static constexpr size_t WSB_MT      = 48496640;   // bf16 [768][768]  (M^T)
static constexpr size_t WSB_PARTU   = 49676288;   // f32 [512][768]
static constexpr size_t WSB_PARTM   = 51249152;   // f32 [128][768]
static constexpr size_t WSB_KBAR    = 51642368;   // f64 [768]
static constexpr size_t WSB_QBAR    = 51648512;   // f64 [768]
static constexpr size_t WSB_U       = 51654656;   // f64 [768]
static constexpr size_t WSB_V       = 51660800;   // f64 [768]
static constexpr size_t WSB_VA      = 51666944;   // f64 [768]
static constexpr size_t WSB_VB      = 51673088;   // f64 [768]
static constexpr size_t WSB_CONSTS  = 51679232;   // f64 [4]
static constexpr size_t WSB_QS      = 51679296;   // f32 [8192]
static constexpr size_t WSB_KQ      = 51712064;   // f32 [8192]
static constexpr size_t WSB_GA      = 51744832;   // f32 [8192]
static constexpr size_t WSB_GB      = 51777600;   // f32 [8192]
static constexpr size_t WSB_COLSUM  = 51810368;   // f32 [8192]
static constexpr size_t WSB_FLAGS   = 51843136;   // int [8192]
static constexpr size_t WSB_ROWSUM  = 51875904;   // f32 [8192]
static constexpr size_t WSB_UVU     = 51908672;   // f64 [8][768]
static constexpr size_t WSB_UVV     = 51957824;   // f64 [8][768]
static constexpr size_t WSB_UVA     = 52006976;   // f64 [8][768]
static constexpr size_t WSB_UVB     = 52056128;   // f64 [8][768]

typedef __attribute__((ext_vector_type(8))) short short8;
typedef __attribute__((ext_vector_type(4))) float f32x4;

static __device__ __forceinline__ ushort f2bf(float f) {
    union { float f; unsigned u; } v; v.f = f;
    unsigned u = v.u;
    unsigned r = (u + 0x7FFFu + ((u >> 16) & 1u)) >> 16;
    return (ushort)r;
}

static __device__ __forceinline__ void gload16(const void* g, void* lds) {
    __builtin_amdgcn_global_load_lds(
        (const __attribute__((address_space(1))) void*)g,
        (__attribute__((address_space(3))) void*)lds, 16, 0, 0);
}

static __device__ __forceinline__ void fmax4(float4& a, const float4& x) {
    a.x = fmaxf(a.x, x.x); a.y = fmaxf(a.y, x.y);
    a.z = fmaxf(a.z, x.z); a.w = fmaxf(a.w, x.w);
}

// ---------------------------------------------------------------------------
// fold1: blocks 0..191 kbar/qbar row sums; 192..1343 transpose-convert
// K_w->KwbT, Q_w->QwbT (bf16, [i][e]); 1344 colsum zero.
__global__ __launch_bounds__(256)
void fold1(const float* __restrict__ K_w, const float* __restrict__ K_b,
           const float* __restrict__ Q_w, const float* __restrict__ Q_b,
           double* __restrict__ kbar, double* __restrict__ qbar,
           ushort* __restrict__ KwbT, ushort* __restrict__ QwbT,
           float* __restrict__ colsum) {
    int blk = blockIdx.x, t = threadIdx.x;
    if (blk < 192) {
        int wv = t >> 6, lane = t & 63;
        int r = blk * 4 + wv;
        double sk = 0.0, sq = 0.0;
        for (int d = lane; d < Dn; d += 64) {
            sk += (double)K_w[(size_t)r * Dn + d];
            sq += (double)Q_w[(size_t)r * Dn + d];
        }
        #pragma unroll
        for (int off = 32; off > 0; off >>= 1) {
            sk += __shfl_down(sk, off, 64);
            sq += __shfl_down(sq, off, 64);
        }
        if (lane == 0) {
            kbar[r] = -1e12 * sk + (double)K_b[r];
            qbar[r] = -1e12 * sq + (double)Q_b[r];
        }
    } else if (blk < 1344) {
        int tt = blk - 192;                         // 0..1151
        const float* src = (tt < 576) ? K_w : Q_w;
        ushort* dst = (tt < 576) ? KwbT : QwbT;
        int t6 = (tt < 576) ? tt : tt - 576;
        int e0 = (t6 % 24) * 32, i0 = (t6 / 24) * 32;
        __shared__ ushort tile[32][33];
        int tx = t & 31, ty = t >> 5;
        #pragma unroll
        for (int i2 = 0; i2 < 4; ++i2)
            tile[ty + i2 * 8][tx] = f2bf(src[(size_t)(e0 + ty + i2 * 8) * Dn + i0 + tx]);
        __syncthreads();
        #pragma unroll
        for (int i2 = 0; i2 < 4; ++i2)
            dst[(size_t)(i0 + ty + i2 * 8) * Dn + e0 + tx] = tile[tx][ty + i2 * 8];
    } else {
        for (int i = t; i < Bn * Sn; i += 256) colsum[i] = 0.f;
    }
}

// ---------------------------------------------------------------------------
// Merged: blocks 0..511 adj softmax + rowsum + colsum partials;
//         blocks 512..523 u/v/a/b fold partials (8-way e-chunks).
__global__ __launch_bounds__(512)
void adjsm_uv_kernel(const float* __restrict__ adj, float* __restrict__ adjsm,
                     float* __restrict__ colsum, float* __restrict__ rowsum,
                     const float* __restrict__ K_w, const float* __restrict__ Q_w,
                     const float* __restrict__ K_b, const float* __restrict__ Q_b,
                     const double* __restrict__ kbar, const double* __restrict__ qbar,
                     double* __restrict__ uvu, double* __restrict__ uvv,
                     double* __restrict__ uva, double* __restrict__ uvb) {
    int blk = blockIdx.x;
    int t = threadIdx.x;
    if (blk >= 512) {
        int id = (blk - 512) * 512 + t;     // 0..6143 = 8 chunks x 768 j
        int c = id / 768;
        int j = id - c * 768;
        int e0 = c * 96;
        double su = 0.0, sv = 0.0, sa = 0.0, sb = 0.0;
        for (int e = e0; e < e0 + 96; ++e) {
            double kw = (double)K_w[(size_t)e * Dn + j];
            double qw = (double)Q_w[(size_t)e * Dn + j];
            su += kw * qbar[e];
            sv += qw * kbar[e];
            sa += kw * (double)Q_b[e];
            sb += qw * (double)K_b[e];
        }
        uvu[(size_t)c * Dn + j] = su;
        uvv[(size_t)c * Dn + j] = sv;
        uva[(size_t)c * Dn + j] = sa;
        uvb[(size_t)c * Dn + j] = sb;
        return;
    }
    int b = blk >> 5, rc = blk & 31;
    const float* base = adj + ((size_t)b * Sn + rc * 16) * Sn;
    float* obase = adjsm + ((size_t)b * Sn + rc * 16) * Sn;
    const float EM1 = 0.36787944117144233f;   // exp(-1)
    const float EP1 = 2.718281828459045f;     // exp(+1)
    __shared__ float red[8];
    float colacc = 0.f;
    for (int r = 0; r < 16; ++r) {
        float a = base[(size_t)r * Sn + t];
        colacc += a;
        float s = a;
        #pragma unroll
        for (int off = 32; off > 0; off >>= 1) s += __shfl_down(s, off, 64);
        if ((t & 63) == 0) red[t >> 6] = s;
        __syncthreads();
        float n1 = red[0] + red[1] + red[2] + red[3]
                 + red[4] + red[5] + red[6] + red[7];
        float e1, e0;
        if (n1 > 0.f) { e1 = 1.f; e0 = EM1; } else { e1 = EP1; e0 = 1.f; }
        float denom = n1 * e1 + (512.f - n1) * e0;
        float inv = 1.f / denom;
        obase[(size_t)r * Sn + t] = (a == 1.f ? e1 : e0) * inv;
        if (t == 0) rowsum[(size_t)b * Sn + rc * 16 + r] = n1;
        __syncthreads();
    }
    atomicAdd(&colsum[(size_t)b * Sn + t], colacc);
}

// blocks 0..11: reduce u/v/a/b; block 12: consts c0..c3
__global__ __launch_bounds__(64)
void uvred_consts(const double* __restrict__ uvu, const double* __restrict__ uvv,
                  const double* __restrict__ uva, const double* __restrict__ uvb,
                  const double* __restrict__ kbar, const double* __restrict__ qbar,
                  const float* __restrict__ K_b, const float* __restrict__ Q_b,
                  double* __restrict__ u, double* __restrict__ v,
                  double* __restrict__ va, double* __restrict__ vb,
                  double* __restrict__ consts) {
    int blk = blockIdx.x;
    int l = threadIdx.x;
    if (blk < 12) {
        int j = blk * 64 + l;
        double su = 0.0, sv = 0.0, sa = 0.0, sb = 0.0;
        #pragma unroll
        for (int c = 0; c < 8; ++c) {
            su += uvu[(size_t)c * Dn + j];
            sv += uvv[(size_t)c * Dn + j];
            sa += uva[(size_t)c * Dn + j];
            sb += uvb[(size_t)c * Dn + j];
        }
        u[j] = su; v[j] = sv; va[j] = sa; vb[j] = sb;
    } else {
        double c0 = 0.0, c1 = 0.0, c2 = 0.0, c3 = 0.0;
        for (int e = l; e < Dn; e += 64) {
            c0 += kbar[e] * (double)Q_b[e];
            c1 += kbar[e] * qbar[e];
            c2 += qbar[e] * (double)K_b[e];
            c3 += (double)K_b[e] * (double)Q_b[e];
        }
        #pragma unroll
        for (int off = 32; off > 0; off >>= 1) {
            c0 += __shfl_down(c0, off, 64);
            c1 += __shfl_down(c1, off, 64);
            c2 += __shfl_down(c2, off, 64);
            c3 += __shfl_down(c3, off, 64);
        }
        if (l == 0) { consts[0] = c0; consts[1] = c1; consts[2] = c2; consts[3] = c3; }
    }
}

// ---------------------------------------------------------------------------
// merged: blocks 0..8191 = g pool (+f64 dots); 8192..8319 main s1; 8320..8831 user s1
__global__ __launch_bounds__(192)
void pool_g_s1(const int* __restrict__ words, const int* __restrict__ masks,
               const int* __restrict__ main_idx, const int* __restrict__ mmask,
               const int* __restrict__ user_idx, const int* __restrict__ umask,
               const float* __restrict__ emb,
               const double* __restrict__ u, const double* __restrict__ v,
               const double* __restrict__ va, const double* __restrict__ vb,
               const double* __restrict__ consts,
               ushort* __restrict__ gbf, float* __restrict__ qs,
               float* __restrict__ kq, float* __restrict__ ga,
               float* __restrict__ gb, int* __restrict__ flags,
               float* __restrict__ partM, float* __restrict__ partU) {
    int blk = blockIdx.x;
    int t = threadIdx.x;
    if (blk >= Bn * Sn) {
        int s1 = blk - Bn * Sn;
        const int *irow, *mrow;
        float* dst;
        if (s1 < 128) {
            int bm = s1 >> 2, ch = s1 & 3;
            irow = main_idx + (size_t)bm * WMn + ch * 16;
            mrow = mmask + (size_t)bm * WMn + ch * 16;
            dst = partM + (size_t)s1 * Dn;
        } else {
            int bu = s1 - 128;
            irow = user_idx + (size_t)bu * WUn;
            mrow = umask + (size_t)bu * WUn;
            dst = partU + (size_t)bu * Dn;
        }
        float4 acc = make_float4(-INF_VAL, -INF_VAL, -INF_VAL, -INF_VAL);
        #pragma unroll
        for (int w = 0; w < 16; ++w) {
            if (mrow[w] != 0) continue;
            float4 x = ((const float4*)(emb + (size_t)irow[w] * Dn))[t];
            fmax4(acc, x);
        }
        ((float4*)dst)[t] = acc;
        return;
    }
    int bs = blk;
    const int* wrow = words + (size_t)bs * Wn;
    const int* mrow = masks + (size_t)bs * Wn;
    float4 acc = make_float4(-INF_VAL, -INF_VAL, -INF_VAL, -INF_VAL);
    int nm = 0;
    #pragma unroll
    for (int w = 0; w < Wn; ++w) {
        int mk = mrow[w];
        nm += (mk != 0);
        if (mk != 0) continue;
        float4 x = ((const float4*)(emb + (size_t)wrow[w] * Dn))[t];
        fmax4(acc, x);
    }
    ushort4 o;
    o.x = f2bf(acc.x); o.y = f2bf(acc.y); o.z = f2bf(acc.z); o.w = f2bf(acc.w);
    ((ushort4*)(gbf + (size_t)bs * Dn))[t] = o;
    int j = t * 4;
    double dv = v[j] * (double)acc.x + v[j+1] * (double)acc.y
              + v[j+2] * (double)acc.z + v[j+3] * (double)acc.w;
    double du = u[j] * (double)acc.x + u[j+1] * (double)acc.y
              + u[j+2] * (double)acc.z + u[j+3] * (double)acc.w;
    double da = va[j] * (double)acc.x + va[j+1] * (double)acc.y
              + va[j+2] * (double)acc.z + va[j+3] * (double)acc.w;
    double db = vb[j] * (double)acc.x + vb[j+1] * (double)acc.y
              + vb[j+2] * (double)acc.z + vb[j+3] * (double)acc.w;
    #pragma unroll
    for (int off = 32; off > 0; off >>= 1) {
        dv += __shfl_down(dv, off, 64);
        du += __shfl_down(du, off, 64);
        da += __shfl_down(da, off, 64);
        db += __shfl_down(db, off, 64);
    }
    __shared__ double rr[12];
    if ((t & 63) == 0) {
        rr[t >> 6] = dv; rr[3 + (t >> 6)] = du;
        rr[6 + (t >> 6)] = da; rr[9 + (t >> 6)] = db;
    }
    __syncthreads();
    if (t == 0) {
        qs[bs] = (float)(rr[0] + rr[1] + rr[2] + consts[0]);
        kq[bs] = (float)(rr[3] + rr[4] + rr[5] + consts[2]);
        ga[bs] = (float)(rr[6] + rr[7] + rr[8]);
        gb[bs] = (float)(rr[9] + rr[10] + rr[11]);
        flags[bs] = (nm == Wn) ? 1 : 0;
    }
}

// ---------------------------------------------------------------------------
// merged mid: blocks 0..6143 transpose g->gT; 6144..6175 main s2; 6176..6191
// user s2; 6192..6223 node mask.
__global__ __launch_bounds__(256)
void mid_kernel(const ushort* __restrict__ gbf, ushort* __restrict__ gT,
                const float* __restrict__ partM, const float* __restrict__ partU,
                float* __restrict__ outM, float* __restrict__ outU,
                const float* __restrict__ rowsum, const float* __restrict__ colsum,
                float* __restrict__ maskout) {
    int blk = blockIdx.x;
    int t = threadIdx.x;
    if (blk < 6144) {
        __shared__ ushort tile[32][33];
        int b = blk / 384;
        int rem = blk - b * 384;
        int d0 = (rem % 24) * 32, s0 = (rem / 24) * 32;
        int tx = t & 31, ty = t >> 5;
        #pragma unroll
        for (int i = 0; i < 4; ++i)
            tile[ty + i * 8][tx] = gbf[((size_t)(b * Sn + s0 + ty + i * 8)) * Dn + d0 + tx];
        __syncthreads();
        #pragma unroll
        for (int i = 0; i < 4; ++i)
            gT[((size_t)(b * Dn + d0 + ty + i * 8)) * Sn + s0 + tx] = tile[tx][ty + i * 8];
        return;
    }
    if (blk >= 6192) {
        int i = (blk - 6192) * 256 + t;
        if (i < Bn * Sn)
            maskout[i] = ((rowsum[i] + colsum[i]) == 0.f) ? 1.f : 0.f;
        return;
    }
    if (t >= 192) return;
    float4 acc = make_float4(-INF_VAL, -INF_VAL, -INF_VAL, -INF_VAL);
    float* dst;
    if (blk < 6176) {
        int bm = blk - 6144;
        #pragma unroll
        for (int c = 0; c < 4; ++c) {
            float4 x = ((const float4*)(partM + (size_t)(bm * 4 + c) * Dn))[t];
            fmax4(acc, x);
        }
        dst = outM + (size_t)bm * Dn;
    } else {
        int b = blk - 6176;
        for (int u2 = 0; u2 < Un; ++u2) {
            float4 x = ((const float4*)(partU + (size_t)(b * Un + u2) * Dn))[t];
            fmax4(acc, x);
        }
        dst = outU + (size_t)b * Dn;
    }
    if (acc.x == -INF_VAL) acc.x = 0.f;
    if (acc.y == -INF_VAL) acc.y = 0.f;
    if (acc.z == -INF_VAL) acc.z = 0.f;
    if (acc.w == -INF_VAL) acc.w = 0.f;
    ((float4*)dst)[t] = acc;
}

// ---------------------------------------------------------------------------
// bf16 MFMA GEMM: C[m][n] = sum_k A[m][k]*B[n][k]
// 128x64 tile, BK=128 (48 KB LDS, 3 blocks/CU), 256 threads = 4 waves (2x2).
// 32 MFMA per barrier (2x the BK=64 version) to amortize the barrier drain.
// XOR chunk swizzle over 16 chunks/row: cc = c16 ^ (row & 15).
template<int OUT_BF16>
__global__ __launch_bounds__(256)
void gemm_mfma(const ushort* __restrict__ A, const ushort* __restrict__ B,
               void* __restrict__ Cout,
               int Km, int lda, int ldb, int ldc,
               long long sA, long long sB, long long sC) {
    __shared__ ushort As[128 * 128];   // 32 KB
    __shared__ ushort Bs[64 * 128];    // 16 KB
    const ushort* Ab = A + (size_t)blockIdx.z * sA;
    const ushort* Bb = B + (size_t)blockIdx.z * sB;
    int i0 = blockIdx.y * 128, j0 = blockIdx.x * 64;
    int tid = threadIdx.x;
    int lane = tid & 63, wv = tid >> 6;
    int wr = wv >> 1, wc = wv & 1;
    int ln15 = lane & 15, lkg = lane >> 4;
    int r4 = lane >> 4;       // row within 4-row group
    int c16 = lane & 15;      // 16B chunk index

    f32x4 acc[4][2] = {};

    for (int k0 = 0; k0 < Km; k0 += 128) {
        #pragma unroll
        for (int it = 0; it < 8; ++it) {
            int r = it * 16 + wv * 4 + r4;
            int cc = c16 ^ (r & 15);
            ushort* dstA = As + (it * 4096 + wv * 1024) / 2;   // wave-uniform
            gload16(Ab + (size_t)(i0 + r) * lda + k0 + cc * 8, dstA);
        }
        #pragma unroll
        for (int it = 0; it < 4; ++it) {
            int r = it * 16 + wv * 4 + r4;
            int cc = c16 ^ (r & 15);
            ushort* dstB = Bs + (it * 4096 + wv * 1024) / 2;
            gload16(Bb + (size_t)(j0 + r) * ldb + k0 + cc * 8, dstB);
        }
        __syncthreads();
        #pragma unroll
        for (int kh = 0; kh < 4; ++kh) {
            short8 af[4], bfr[2];
            int kc = kh * 4 + lkg;
            #pragma unroll
            for (int f = 0; f < 4; ++f) {
                int ra = wr * 64 + f * 16 + ln15;
                af[f] = *(const short8*)((const char*)As + ra * 256 + ((kc ^ (ra & 15)) << 4));
            }
            #pragma unroll
            for (int f = 0; f < 2; ++f) {
                int rb = wc * 32 + f * 16 + ln15;
                bfr[f] = *(const short8*)((const char*)Bs + rb * 256 + ((kc ^ (rb & 15)) << 4));
            }
            #pragma unroll
            for (int fa = 0; fa < 4; ++fa)
                #pragma unroll
                for (int fb = 0; fb < 2; ++fb)
                    acc[fa][fb] = __builtin_amdgcn_mfma_f32_16x16x32_bf16(
                        af[fa], bfr[fb], acc[fa][fb], 0, 0, 0);
        }
        __syncthreads();
    }

    #pragma unroll
    for (int fa = 0; fa < 4; ++fa) {
        #pragma unroll
        for (int fb = 0; fb < 2; ++fb) {
            int n = j0 + wc * 32 + fb * 16 + ln15;
            #pragma unroll
            for (int rr = 0; rr < 4; ++rr) {
                int m = i0 + wr * 64 + fa * 16 + lkg * 4 + rr;
                float val = acc[fa][fb][rr];
                if (OUT_BF16) {
                    ((ushort*)Cout)[(size_t)blockIdx.z * sC + (size_t)m * ldc + n] = f2bf(val);
                } else {
                    ((float*)Cout)[(size_t)blockIdx.z * sC + (size_t)m * ldc + n] = val;
                }
            }
        }
    }
}

// ---------------------------------------------------------------------------
// scores fixup + bias-rank1 correction + row softmax.
__global__ __launch_bounds__(256)
void softmax_fix(float* __restrict__ dense, const int* __restrict__ flags,
                 const float* __restrict__ qs, const float* __restrict__ kq,
                 const float* __restrict__ ga, const float* __restrict__ gb,
                 const double* __restrict__ consts, ushort* __restrict__ densebf) {
    int bs = blockIdx.x;
    int b = bs >> 9;
    int t = threadIdx.x;
    float* row = dense + (size_t)bs * 512;
    int f0 = flags[(b << 9) + t];
    int f1 = flags[(b << 9) + t + 256];
    bool sm = flags[bs] != 0;
    float x0, x1;
    if (sm) {
        float c1i = (float)consts[1] * INV_SQRT_D;
        x0 = f0 ? c1i : qs[(b << 9) + t] * INV_SQRT_D;
        x1 = f1 ? c1i : qs[(b << 9) + t + 256] * INV_SQRT_D;
    } else {
        float kqi = kq[bs] * INV_SQRT_D;
        float corr = ga[bs] + (float)consts[3];
        x0 = f0 ? kqi : (row[t] + corr + gb[(b << 9) + t]) * INV_SQRT_D;
        x1 = f1 ? kqi : (row[t + 256] + corr + gb[(b << 9) + t + 256]) * INV_SQRT_D;
    }
    float m = fmaxf(x0, x1);
    #pragma unroll
    for (int off = 32; off > 0; off >>= 1) m = fmaxf(m, __shfl_down(m, off, 64));
    __shared__ float red[4];
    __shared__ float bmax, bsum;
    if ((t & 63) == 0) red[t >> 6] = m;
    __syncthreads();
    if (t == 0) bmax = fmaxf(fmaxf(red[0], red[1]), fmaxf(red[2], red[3]));
    __syncthreads();
    float mx = bmax;
    float e0 = expf(x0 - mx), e1 = expf(x1 - mx);
    float s = e0 + e1;
    #pragma unroll
    for (int off = 32; off > 0; off >>= 1) s += __shfl_down(s, off, 64);
    if ((t & 63) == 0) red[t >> 6] = s;
    __syncthreads();
    if (t == 0) bsum = red[0] + red[1] + red[2] + red[3];
    __syncthreads();
    float inv = 1.f / bsum;
    float p0 = e0 * inv, p1 = e1 * inv;
    row[t] = p0; row[t + 256] = p1;
    ushort* bro = densebf + (size_t)bs * 512;
    bro[t] = f2bf(p0); bro[t + 256] = f2bf(p1);
}

// ---------------------------------------------------------------------------
extern "C" void kernel_launch(void* const* d_in, const int* in_sizes, int n_in,
                              void* d_out, int out_size, void* d_ws, size_t ws_size,
                              hipStream_t stream) {
    const int*   words     = (const int*)d_in[0];
    const int*   masks     = (const int*)d_in[1];
    const int*   main_idx  = (const int*)d_in[2];
    const int*   main_mask = (const int*)d_in[3];
    const int*   user_idx  = (const int*)d_in[4];
    const int*   user_mask = (const int*)d_in[5];
    const float* adj       = (const float*)d_in[6];
    const float* emb       = (const float*)d_in[7];
    const float* K_w       = (const float*)d_in[8];
    const float* K_b       = (const float*)d_in[9];
    const float* Q_w       = (const float*)d_in[10];
    const float* Q_b       = (const float*)d_in[11];

    float* out = (float*)d_out;
    char*  ws8 = (char*)d_ws;

    ushort* gbf     = (ushort*)(ws8 + WSB_GBF);
    ushort* gT      = (ushort*)(ws8 + WSB_GT);
    ushort* densebf = (ushort*)(ws8 + WSB_DENSEBF);
    ushort* hbf     = (ushort*)(ws8 + WSB_HBF);
    ushort* KwbT    = (ushort*)(ws8 + WSB_KWT);
    ushort* QwbT    = (ushort*)(ws8 + WSB_QWT);
    ushort* Mt      = (ushort*)(ws8 + WSB_MT);
    float*  partU   = (float*)(ws8 + WSB_PARTU);
    float*  partM   = (float*)(ws8 + WSB_PARTM);
    double* kbar    = (double*)(ws8 + WSB_KBAR);
    double* qbar    = (double*)(ws8 + WSB_QBAR);
    double* u       = (double*)(ws8 + WSB_U);
    double* v       = (double*)(ws8 + WSB_V);
    double* va      = (double*)(ws8 + WSB_VA);
    double* vb      = (double*)(ws8 + WSB_VB);
    double* consts  = (double*)(ws8 + WSB_CONSTS);
    float*  qs      = (float*)(ws8 + WSB_QS);
    float*  kq      = (float*)(ws8 + WSB_KQ);
    float*  ga      = (float*)(ws8 + WSB_GA);
    float*  gb      = (float*)(ws8 + WSB_GB);
    float*  colsum  = (float*)(ws8 + WSB_COLSUM);
    int*    flags   = (int*)(ws8 + WSB_FLAGS);
    float*  rowsum  = (float*)(ws8 + WSB_ROWSUM);
    double* uvu     = (double*)(ws8 + WSB_UVU);
    double* uvv     = (double*)(ws8 + WSB_UVV);
    double* uva     = (double*)(ws8 + WSB_UVA);
    double* uvb     = (double*)(ws8 + WSB_UVB);

    float* dense = out + OFF_DENSE;

    // 1: weight row-sums + transposed bf16 converts + colsum zero
    fold1<<<1345, 256, 0, stream>>>(K_w, K_b, Q_w, Q_b, kbar, qbar, KwbT, QwbT, colsum);

    // 2: adj softmax + rowsum/colsum  ∥  u/v/a/b fold partials (merged)
    adjsm_uv_kernel<<<524, 512, 0, stream>>>(adj, out + OFF_ADJ, colsum, rowsum,
                                             K_w, Q_w, K_b, Q_b, kbar, qbar,
                                             uvu, uvv, uva, uvb);

    // 3: reduce u/v/a/b + consts
    uvred_consts<<<13, 64, 0, stream>>>(uvu, uvv, uva, uvb, kbar, qbar, K_b, Q_b,
                                        u, v, va, vb, consts);

    // 4: Mt[j][i] = M[i][j] = sum_e Kw[e,i]Qw[e,j]
    gemm_mfma<1><<<dim3(12, 6, 1), 256, 0, stream>>>(
        QwbT, KwbT, Mt, Dn, Dn, Dn, Dn, 0, 0, 0);

    // 5: pools (g + s1 merged)
    pool_g_s1<<<Bn * Sn + 640, 192, 0, stream>>>(
        words, masks, main_idx, main_mask, user_idx, user_mask, emb,
        u, v, va, vb, consts, gbf, qs, kq, ga, gb, flags, partM, partU);

    // 6: transpose g + pool stage2 + node mask (merged)
    mid_kernel<<<6224, 256, 0, stream>>>(gbf, gT, partM, partU,
                                         out + OFF_MAIN, out + OFF_USER,
                                         rowsum, colsum, out + OFF_MASK);

    // 7: h = g @ M
    gemm_mfma<1><<<dim3(12, 64, 1), 256, 0, stream>>>(
        gbf, Mt, hbf, Dn, Dn, Dn, Dn, 0, 0, 0);

    // 8: raw scores[b] = h[b] @ g[b]^T
    gemm_mfma<0><<<dim3(8, 4, Bn), 256, 0, stream>>>(
        hbf, gbf, dense, Dn, Dn, Dn, Sn,
        (long long)Sn * Dn, (long long)Sn * Dn, (long long)Sn * Sn);

    // 9: fixup masked rows/cols + bias rank-1 + softmax
    softmax_fix<<<Bn * Sn, 256, 0, stream>>>(dense, flags, qs, kq, ga, gb, consts, densebf);

    // 10: gcn[b] = P[b] @ g[b]
    gemm_mfma<0><<<dim3(12, 4, Bn), 256, 0, stream>>>(
        densebf, gT, out + OFF_GCN, Sn, Sn, Sn, Dn,
        (long long)Sn * Sn, (long long)Dn * Sn, (long long)Sn * Dn);
}

// Round 10
// 150.454 us; speedup vs baseline: 1.1412x; 1.0454x over previous
//
#include <hip/hip_runtime.h>
#include <hip/hip_bf16.h>
#include <math.h>

// Problem sizes (fixed by reference)
static constexpr int Bn = 16, Sn = 512, Wn = 8, Dn = 768;
static constexpr int Mn_ = 2, WMn = 64;
static constexpr int Un = 32, WUn = 16;

#define INF_VAL 1e12f
#define INV_SQRT_D 0.03608439182435161f

// Output float offsets
static constexpr size_t OFF_GCN   = 0;                    // [16,512,768]
static constexpr size_t OFF_MASK  = 6291456;              // [16,512,1]
static constexpr size_t OFF_DENSE = 6299648;              // [16,512,512]
static constexpr size_t OFF_ADJ   = 10493952;             // [16,512,512]
static constexpr size_t OFF_MAIN  = 14688256;             // [16,2,768]
static constexpr size_t OFF_USER  = 14712832;             // [16,768]

// Workspace byte offsets (~52 MB total; ws is ~393 MB)
static constexpr size_t WSB_GBF     = 0;          // bf16 [8192][768]
static constexpr size_t WSB_GT      = 12582912;   // bf16 [16][768][512]
static constexpr size_t WSB_DENSEBF = 25165824;   // bf16 [8192][512]
static constexpr size_t WSB_HBF     = 33554432;   // bf16 [8192][768]
static constexpr size_t WSB_KWT     = 46137344;   // bf16 [768][768]  (K_w^T)
static constexpr size_t WSB_QWT     = 47316992;   // bf16 [768][768]  (Q_w^T)
static constexpr size_t WSB_MT      = 48496640;   // bf16 [768][768]  (M^T)
static constexpr size_t WSB_PARTU   = 49676288;   // f32 [512][768]
static constexpr size_t WSB_PARTM   = 51249152;   // f32 [128][768]
static constexpr size_t WSB_KBAR    = 51642368;   // f64 [768]
static constexpr size_t WSB_QBAR    = 51648512;   // f64 [768]
static constexpr size_t WSB_U       = 51654656;   // f64 [768]
static constexpr size_t WSB_V       = 51660800;   // f64 [768]
static constexpr size_t WSB_VA      = 51666944;   // f64 [768]
static constexpr size_t WSB_VB      = 51673088;   // f64 [768]
static constexpr size_t WSB_CONSTS  = 51679232;   // f64 [4]
static constexpr size_t WSB_QS      = 51679296;   // f32 [8192]
static constexpr size_t WSB_KQ      = 51712064;   // f32 [8192]
static constexpr size_t WSB_GA      = 51744832;   // f32 [8192]
static constexpr size_t WSB_GB      = 51777600;   // f32 [8192]
static constexpr size_t WSB_COLSUM  = 51810368;   // f32 [8192]
static constexpr size_t WSB_FLAGS   = 51843136;   // int [8192]
static constexpr size_t WSB_ROWSUM  = 51875904;   // f32 [8192]
static constexpr size_t WSB_UVU     = 51908672;   // f64 [8][768]
static constexpr size_t WSB_UVV     = 51957824;   // f64 [8][768]
static constexpr size_t WSB_UVA     = 52006976;   // f64 [8][768]
static constexpr size_t WSB_UVB     = 52056128;   // f64 [8][768]

typedef __attribute__((ext_vector_type(8))) short short8;
typedef __attribute__((ext_vector_type(4))) float f32x4;

static __device__ __forceinline__ ushort f2bf(float f) {
    union { float f; unsigned u; } v; v.f = f;
    unsigned u = v.u;
    unsigned r = (u + 0x7FFFu + ((u >> 16) & 1u)) >> 16;
    return (ushort)r;
}

static __device__ __forceinline__ void gload16(const void* g, void* lds) {
    __builtin_amdgcn_global_load_lds(
        (const __attribute__((address_space(1))) void*)g,
        (__attribute__((address_space(3))) void*)lds, 16, 0, 0);
}

static __device__ __forceinline__ void fmax4(float4& a, const float4& x) {
    a.x = fmaxf(a.x, x.x); a.y = fmaxf(a.y, x.y);
    a.z = fmaxf(a.z, x.z); a.w = fmaxf(a.w, x.w);
}

// ---------------------------------------------------------------------------
// fold1: blocks 0..191 kbar/qbar row sums; 192..1343 transpose-convert
// K_w->KwbT, Q_w->QwbT (bf16, [i][e]); 1344 colsum zero.
__global__ __launch_bounds__(256)
void fold1(const float* __restrict__ K_w, const float* __restrict__ K_b,
           const float* __restrict__ Q_w, const float* __restrict__ Q_b,
           double* __restrict__ kbar, double* __restrict__ qbar,
           ushort* __restrict__ KwbT, ushort* __restrict__ QwbT,
           float* __restrict__ colsum) {
    int blk = blockIdx.x, t = threadIdx.x;
    if (blk < 192) {
        int wv = t >> 6, lane = t & 63;
        int r = blk * 4 + wv;
        double sk = 0.0, sq = 0.0;
        for (int d = lane; d < Dn; d += 64) {
            sk += (double)K_w[(size_t)r * Dn + d];
            sq += (double)Q_w[(size_t)r * Dn + d];
        }
        #pragma unroll
        for (int off = 32; off > 0; off >>= 1) {
            sk += __shfl_down(sk, off, 64);
            sq += __shfl_down(sq, off, 64);
        }
        if (lane == 0) {
            kbar[r] = -1e12 * sk + (double)K_b[r];
            qbar[r] = -1e12 * sq + (double)Q_b[r];
        }
    } else if (blk < 1344) {
        int tt = blk - 192;                         // 0..1151
        const float* src = (tt < 576) ? K_w : Q_w;
        ushort* dst = (tt < 576) ? KwbT : QwbT;
        int t6 = (tt < 576) ? tt : tt - 576;
        int e0 = (t6 % 24) * 32, i0 = (t6 / 24) * 32;
        __shared__ ushort tile[32][33];
        int tx = t & 31, ty = t >> 5;
        #pragma unroll
        for (int i2 = 0; i2 < 4; ++i2)
            tile[ty + i2 * 8][tx] = f2bf(src[(size_t)(e0 + ty + i2 * 8) * Dn + i0 + tx]);
        __syncthreads();
        #pragma unroll
        for (int i2 = 0; i2 < 4; ++i2)
            dst[(size_t)(i0 + ty + i2 * 8) * Dn + e0 + tx] = tile[tx][ty + i2 * 8];
    } else {
        for (int i = t; i < Bn * Sn; i += 256) colsum[i] = 0.f;
    }
}

// ---------------------------------------------------------------------------
// Merged: blocks 0..511 adj softmax (LDS-staged, 2 barriers) + rowsum + colsum;
//         blocks 512..523 u/v/a/b fold partials (8-way e-chunks).
__global__ __launch_bounds__(512)
void adjsm_uv_kernel(const float* __restrict__ adj, float* __restrict__ adjsm,
                     float* __restrict__ colsum, float* __restrict__ rowsum,
                     const float* __restrict__ K_w, const float* __restrict__ Q_w,
                     const float* __restrict__ K_b, const float* __restrict__ Q_b,
                     const double* __restrict__ kbar, const double* __restrict__ qbar,
                     double* __restrict__ uvu, double* __restrict__ uvv,
                     double* __restrict__ uva, double* __restrict__ uvb) {
    int blk = blockIdx.x;
    int t = threadIdx.x;
    if (blk >= 512) {
        int id = (blk - 512) * 512 + t;     // 0..6143 = 8 chunks x 768 j
        int c = id / 768;
        int j = id - c * 768;
        int e0 = c * 96;
        double su = 0.0, sv = 0.0, sa = 0.0, sb = 0.0;
        for (int e = e0; e < e0 + 96; ++e) {
            double kw = (double)K_w[(size_t)e * Dn + j];
            double qw = (double)Q_w[(size_t)e * Dn + j];
            su += kw * qbar[e];
            sv += qw * kbar[e];
            sa += kw * (double)Q_b[e];
            sb += qw * (double)K_b[e];
        }
        uvu[(size_t)c * Dn + j] = su;
        uvv[(size_t)c * Dn + j] = sv;
        uva[(size_t)c * Dn + j] = sa;
        uvb[(size_t)c * Dn + j] = sb;
        return;
    }
    int b = blk >> 5, rc = blk & 31;
    const float* base = adj + ((size_t)b * Sn + rc * 16) * Sn;
    float* obase = adjsm + ((size_t)b * Sn + rc * 16) * Sn;
    const float EM1 = 0.36787944117144233f;   // exp(-1)
    const float EP1 = 2.718281828459045f;     // exp(+1)
    __shared__ float rows[16][512];
    __shared__ float n1s[16];
    // stage 16 rows
    #pragma unroll
    for (int r = 0; r < 16; ++r) rows[r][t] = base[(size_t)r * Sn + t];
    __syncthreads();
    // per-wave rowsums: wave w handles rows 2w, 2w+1 (shuffle-only, exact int sums)
    int wv = t >> 6, lane = t & 63;
    #pragma unroll
    for (int rr2 = 0; rr2 < 2; ++rr2) {
        int r = wv * 2 + rr2;
        float s = 0.f;
        #pragma unroll
        for (int c = 0; c < 8; ++c) s += rows[r][lane + c * 64];
        #pragma unroll
        for (int off = 32; off > 0; off >>= 1) s += __shfl_down(s, off, 64);
        if (lane == 0) {
            n1s[r] = s;
            rowsum[(size_t)b * Sn + rc * 16 + r] = s;
        }
    }
    __syncthreads();
    // emit softmax + column accumulation
    float colacc = 0.f;
    #pragma unroll
    for (int r = 0; r < 16; ++r) {
        float a = rows[r][t];
        colacc += a;
        float n1 = n1s[r];
        float e1, e0;
        if (n1 > 0.f) { e1 = 1.f; e0 = EM1; } else { e1 = EP1; e0 = 1.f; }
        float inv = 1.f / (n1 * e1 + (512.f - n1) * e0);
        obase[(size_t)r * Sn + t] = (a == 1.f ? e1 : e0) * inv;
    }
    atomicAdd(&colsum[(size_t)b * Sn + t], colacc);
}

// ---------------------------------------------------------------------------
// merged uvmt: blocks 0..71 Mt GEMM (declared below via template); here the
// reduce part lives in the same kernel via block-range branch.
// (GEMM body shared through gemm_device().)
template<int OUT_BF16>
static __device__ __forceinline__
void gemm_device(const ushort* __restrict__ A, const ushort* __restrict__ B,
                 void* __restrict__ Cout, int bx, int by, int bz,
                 int Km, int lda, int ldb, int ldc,
                 long long sA, long long sB, long long sC,
                 ushort* As, ushort* Bs) {
    const ushort* Ab = A + (size_t)bz * sA;
    const ushort* Bb = B + (size_t)bz * sB;
    int i0 = by * 128, j0 = bx * 64;
    int tid = threadIdx.x;
    int lane = tid & 63, wv = tid >> 6;
    int wr = wv >> 1, wc = wv & 1;
    int ln15 = lane & 15, lkg = lane >> 4;
    int r4 = lane >> 4;
    int c16 = lane & 15;

    f32x4 acc[4][2] = {};

    for (int k0 = 0; k0 < Km; k0 += 128) {
        #pragma unroll
        for (int it = 0; it < 8; ++it) {
            int r = it * 16 + wv * 4 + r4;
            int cc = c16 ^ (r & 15);
            ushort* dstA = As + (it * 4096 + wv * 1024) / 2;
            gload16(Ab + (size_t)(i0 + r) * lda + k0 + cc * 8, dstA);
        }
        #pragma unroll
        for (int it = 0; it < 4; ++it) {
            int r = it * 16 + wv * 4 + r4;
            int cc = c16 ^ (r & 15);
            ushort* dstB = Bs + (it * 4096 + wv * 1024) / 2;
            gload16(Bb + (size_t)(j0 + r) * ldb + k0 + cc * 8, dstB);
        }
        __syncthreads();
        #pragma unroll
        for (int kh = 0; kh < 4; ++kh) {
            short8 af[4], bfr[2];
            int kc = kh * 4 + lkg;
            #pragma unroll
            for (int f = 0; f < 4; ++f) {
                int ra = wr * 64 + f * 16 + ln15;
                af[f] = *(const short8*)((const char*)As + ra * 256 + ((kc ^ (ra & 15)) << 4));
            }
            #pragma unroll
            for (int f = 0; f < 2; ++f) {
                int rb = wc * 32 + f * 16 + ln15;
                bfr[f] = *(const short8*)((const char*)Bs + rb * 256 + ((kc ^ (rb & 15)) << 4));
            }
            #pragma unroll
            for (int fa = 0; fa < 4; ++fa)
                #pragma unroll
                for (int fb = 0; fb < 2; ++fb)
                    acc[fa][fb] = __builtin_amdgcn_mfma_f32_16x16x32_bf16(
                        af[fa], bfr[fb], acc[fa][fb], 0, 0, 0);
        }
        __syncthreads();
    }

    #pragma unroll
    for (int fa = 0; fa < 4; ++fa) {
        #pragma unroll
        for (int fb = 0; fb < 2; ++fb) {
            int n = j0 + wc * 32 + fb * 16 + ln15;
            #pragma unroll
            for (int rr = 0; rr < 4; ++rr) {
                int m = i0 + wr * 64 + fa * 16 + lkg * 4 + rr;
                float val = acc[fa][fb][rr];
                if (OUT_BF16) {
                    ((ushort*)Cout)[(size_t)bz * sC + (size_t)m * ldc + n] = f2bf(val);
                } else {
                    ((float*)Cout)[(size_t)bz * sC + (size_t)m * ldc + n] = val;
                }
            }
        }
    }
}

// standalone GEMM kernel
template<int OUT_BF16>
__global__ __launch_bounds__(256)
void gemm_mfma(const ushort* __restrict__ A, const ushort* __restrict__ B,
               void* __restrict__ Cout,
               int Km, int lda, int ldb, int ldc,
               long long sA, long long sB, long long sC) {
    __shared__ ushort As[128 * 128];
    __shared__ ushort Bs[64 * 128];
    gemm_device<OUT_BF16>(A, B, Cout, blockIdx.x, blockIdx.y, blockIdx.z,
                          Km, lda, ldb, ldc, sA, sB, sC, As, Bs);
}

// uvmt: blocks 0..71 = Mt GEMM (12x6 tiles); 72..74 = u/v/a/b reduce; 75 = consts
__global__ __launch_bounds__(256)
void uvmt_kernel(const ushort* __restrict__ QwbT, const ushort* __restrict__ KwbT,
                 ushort* __restrict__ Mt,
                 const double* __restrict__ uvu, const double* __restrict__ uvv,
                 const double* __restrict__ uva, const double* __restrict__ uvb,
                 const double* __restrict__ kbar, const double* __restrict__ qbar,
                 const float* __restrict__ K_b, const float* __restrict__ Q_b,
                 double* __restrict__ u, double* __restrict__ v,
                 double* __restrict__ va, double* __restrict__ vb,
                 double* __restrict__ consts) {
    __shared__ ushort As[128 * 128];
    __shared__ ushort Bs[64 * 128];
    int blk = blockIdx.x;
    int t = threadIdx.x;
    if (blk < 72) {
        gemm_device<1>(QwbT, KwbT, Mt, blk % 12, blk / 12, 0,
                       Dn, Dn, Dn, Dn, 0, 0, 0, As, Bs);
        return;
    }
    if (blk < 75) {
        int j = (blk - 72) * 256 + t;
        double su = 0.0, sv = 0.0, sa = 0.0, sb = 0.0;
        #pragma unroll
        for (int c = 0; c < 8; ++c) {
            su += uvu[(size_t)c * Dn + j];
            sv += uvv[(size_t)c * Dn + j];
            sa += uva[(size_t)c * Dn + j];
            sb += uvb[(size_t)c * Dn + j];
        }
        u[j] = su; v[j] = sv; va[j] = sa; vb[j] = sb;
        return;
    }
    if (t >= 64) return;
    int l = t;
    double c0 = 0.0, c1 = 0.0, c2 = 0.0, c3 = 0.0;
    for (int e = l; e < Dn; e += 64) {
        c0 += kbar[e] * (double)Q_b[e];
        c1 += kbar[e] * qbar[e];
        c2 += qbar[e] * (double)K_b[e];
        c3 += (double)K_b[e] * (double)Q_b[e];
    }
    #pragma unroll
    for (int off = 32; off > 0; off >>= 1) {
        c0 += __shfl_down(c0, off, 64);
        c1 += __shfl_down(c1, off, 64);
        c2 += __shfl_down(c2, off, 64);
        c3 += __shfl_down(c3, off, 64);
    }
    if (l == 0) { consts[0] = c0; consts[1] = c1; consts[2] = c2; consts[3] = c3; }
}

// ---------------------------------------------------------------------------
// merged: blocks 0..8191 = g pool (+f64 dots); 8192..8319 main s1; 8320..8831 user s1
__global__ __launch_bounds__(192)
void pool_g_s1(const int* __restrict__ words, const int* __restrict__ masks,
               const int* __restrict__ main_idx, const int* __restrict__ mmask,
               const int* __restrict__ user_idx, const int* __restrict__ umask,
               const float* __restrict__ emb,
               const double* __restrict__ u, const double* __restrict__ v,
               const double* __restrict__ va, const double* __restrict__ vb,
               const double* __restrict__ consts,
               ushort* __restrict__ gbf, float* __restrict__ qs,
               float* __restrict__ kq, float* __restrict__ ga,
               float* __restrict__ gb, int* __restrict__ flags,
               float* __restrict__ partM, float* __restrict__ partU) {
    int blk = blockIdx.x;
    int t = threadIdx.x;
    if (blk >= Bn * Sn) {
        int s1 = blk - Bn * Sn;
        const int *irow, *mrow;
        float* dst;
        if (s1 < 128) {
            int bm = s1 >> 2, ch = s1 & 3;
            irow = main_idx + (size_t)bm * WMn + ch * 16;
            mrow = mmask + (size_t)bm * WMn + ch * 16;
            dst = partM + (size_t)s1 * Dn;
        } else {
            int bu = s1 - 128;
            irow = user_idx + (size_t)bu * WUn;
            mrow = umask + (size_t)bu * WUn;
            dst = partU + (size_t)bu * Dn;
        }
        float4 acc = make_float4(-INF_VAL, -INF_VAL, -INF_VAL, -INF_VAL);
        #pragma unroll
        for (int w = 0; w < 16; ++w) {
            if (mrow[w] != 0) continue;
            float4 x = ((const float4*)(emb + (size_t)irow[w] * Dn))[t];
            fmax4(acc, x);
        }
        ((float4*)dst)[t] = acc;
        return;
    }
    int bs = blk;
    const int* wrow = words + (size_t)bs * Wn;
    const int* mrow = masks + (size_t)bs * Wn;
    float4 acc = make_float4(-INF_VAL, -INF_VAL, -INF_VAL, -INF_VAL);
    int nm = 0;
    #pragma unroll
    for (int w = 0; w < Wn; ++w) {
        int mk = mrow[w];
        nm += (mk != 0);
        if (mk != 0) continue;
        float4 x = ((const float4*)(emb + (size_t)wrow[w] * Dn))[t];
        fmax4(acc, x);
    }
    ushort4 o;
    o.x = f2bf(acc.x); o.y = f2bf(acc.y); o.z = f2bf(acc.z); o.w = f2bf(acc.w);
    ((ushort4*)(gbf + (size_t)bs * Dn))[t] = o;
    int j = t * 4;
    double dv = v[j] * (double)acc.x + v[j+1] * (double)acc.y
              + v[j+2] * (double)acc.z + v[j+3] * (double)acc.w;
    double du = u[j] * (double)acc.x + u[j+1] * (double)acc.y
              + u[j+2] * (double)acc.z + u[j+3] * (double)acc.w;
    double da = va[j] * (double)acc.x + va[j+1] * (double)acc.y
              + va[j+2] * (double)acc.z + va[j+3] * (double)acc.w;
    double db = vb[j] * (double)acc.x + vb[j+1] * (double)acc.y
              + vb[j+2] * (double)acc.z + vb[j+3] * (double)acc.w;
    #pragma unroll
    for (int off = 32; off > 0; off >>= 1) {
        dv += __shfl_down(dv, off, 64);
        du += __shfl_down(du, off, 64);
        da += __shfl_down(da, off, 64);
        db += __shfl_down(db, off, 64);
    }
    __shared__ double rr[12];
    if ((t & 63) == 0) {
        rr[t >> 6] = dv; rr[3 + (t >> 6)] = du;
        rr[6 + (t >> 6)] = da; rr[9 + (t >> 6)] = db;
    }
    __syncthreads();
    if (t == 0) {
        qs[bs] = (float)(rr[0] + rr[1] + rr[2] + consts[0]);
        kq[bs] = (float)(rr[3] + rr[4] + rr[5] + consts[2]);
        ga[bs] = (float)(rr[6] + rr[7] + rr[8]);
        gb[bs] = (float)(rr[9] + rr[10] + rr[11]);
        flags[bs] = (nm == Wn) ? 1 : 0;
    }
}

// ---------------------------------------------------------------------------
// midh: blocks 0..767 = h GEMM (critical path first); 768..6911 transpose;
// 6912..6943 main s2; 6944..6959 user s2; 6960..6991 node mask.
__global__ __launch_bounds__(256)
void midh_kernel(const ushort* __restrict__ gbf, const ushort* __restrict__ Mt,
                 ushort* __restrict__ hbf, ushort* __restrict__ gT,
                 const float* __restrict__ partM, const float* __restrict__ partU,
                 float* __restrict__ outM, float* __restrict__ outU,
                 const float* __restrict__ rowsum, const float* __restrict__ colsum,
                 float* __restrict__ maskout) {
    __shared__ ushort As[128 * 128];
    __shared__ ushort Bs[64 * 128];
    int blk = blockIdx.x;
    int t = threadIdx.x;
    if (blk < 768) {
        gemm_device<1>(gbf, Mt, hbf, blk % 12, blk / 12, 0,
                       Dn, Dn, Dn, Dn, 0, 0, 0, As, Bs);
        return;
    }
    if (blk < 6912) {
        int bb = blk - 768;
        ushort (*tile)[33] = (ushort(*)[33])As;    // reuse GEMM LDS
        int b = bb / 384;
        int rem = bb - b * 384;
        int d0 = (rem % 24) * 32, s0 = (rem / 24) * 32;
        int tx = t & 31, ty = t >> 5;
        #pragma unroll
        for (int i = 0; i < 4; ++i)
            tile[ty + i * 8][tx] = gbf[((size_t)(b * Sn + s0 + ty + i * 8)) * Dn + d0 + tx];
        __syncthreads();
        #pragma unroll
        for (int i = 0; i < 4; ++i)
            gT[((size_t)(b * Dn + d0 + ty + i * 8)) * Sn + s0 + tx] = tile[tx][ty + i * 8];
        return;
    }
    if (blk >= 6960) {
        int i = (blk - 6960) * 256 + t;
        if (i < Bn * Sn)
            maskout[i] = ((rowsum[i] + colsum[i]) == 0.f) ? 1.f : 0.f;
        return;
    }
    if (t >= 192) return;
    float4 acc = make_float4(-INF_VAL, -INF_VAL, -INF_VAL, -INF_VAL);
    float* dst;
    if (blk < 6944) {
        int bm = blk - 6912;
        #pragma unroll
        for (int c = 0; c < 4; ++c) {
            float4 x = ((const float4*)(partM + (size_t)(bm * 4 + c) * Dn))[t];
            fmax4(acc, x);
        }
        dst = outM + (size_t)bm * Dn;
    } else {
        int b = blk - 6944;
        for (int u2 = 0; u2 < Un; ++u2) {
            float4 x = ((const float4*)(partU + (size_t)(b * Un + u2) * Dn))[t];
            fmax4(acc, x);
        }
        dst = outU + (size_t)b * Dn;
    }
    if (acc.x == -INF_VAL) acc.x = 0.f;
    if (acc.y == -INF_VAL) acc.y = 0.f;
    if (acc.z == -INF_VAL) acc.z = 0.f;
    if (acc.w == -INF_VAL) acc.w = 0.f;
    ((float4*)dst)[t] = acc;
}

// ---------------------------------------------------------------------------
// scores fixup + bias-rank1 correction + row softmax.
__global__ __launch_bounds__(256)
void softmax_fix(float* __restrict__ dense, const int* __restrict__ flags,
                 const float* __restrict__ qs, const float* __restrict__ kq,
                 const float* __restrict__ ga, const float* __restrict__ gb,
                 const double* __restrict__ consts, ushort* __restrict__ densebf) {
    int bs = blockIdx.x;
    int b = bs >> 9;
    int t = threadIdx.x;
    float* row = dense + (size_t)bs * 512;
    int f0 = flags[(b << 9) + t];
    int f1 = flags[(b << 9) + t + 256];
    bool sm = flags[bs] != 0;
    float x0, x1;
    if (sm) {
        float c1i = (float)consts[1] * INV_SQRT_D;
        x0 = f0 ? c1i : qs[(b << 9) + t] * INV_SQRT_D;
        x1 = f1 ? c1i : qs[(b << 9) + t + 256] * INV_SQRT_D;
    } else {
        float kqi = kq[bs] * INV_SQRT_D;
        float corr = ga[bs] + (float)consts[3];
        x0 = f0 ? kqi : (row[t] + corr + gb[(b << 9) + t]) * INV_SQRT_D;
        x1 = f1 ? kqi : (row[t + 256] + corr + gb[(b << 9) + t + 256]) * INV_SQRT_D;
    }
    float m = fmaxf(x0, x1);
    #pragma unroll
    for (int off = 32; off > 0; off >>= 1) m = fmaxf(m, __shfl_down(m, off, 64));
    __shared__ float red[4];
    __shared__ float bmax, bsum;
    if ((t & 63) == 0) red[t >> 6] = m;
    __syncthreads();
    if (t == 0) bmax = fmaxf(fmaxf(red[0], red[1]), fmaxf(red[2], red[3]));
    __syncthreads();
    float mx = bmax;
    float e0 = expf(x0 - mx), e1 = expf(x1 - mx);
    float s = e0 + e1;
    #pragma unroll
    for (int off = 32; off > 0; off >>= 1) s += __shfl_down(s, off, 64);
    if ((t & 63) == 0) red[t >> 6] = s;
    __syncthreads();
    if (t == 0) bsum = red[0] + red[1] + red[2] + red[3];
    __syncthreads();
    float inv = 1.f / bsum;
    float p0 = e0 * inv, p1 = e1 * inv;
    row[t] = p0; row[t + 256] = p1;
    ushort* bro = densebf + (size_t)bs * 512;
    bro[t] = f2bf(p0); bro[t + 256] = f2bf(p1);
}

// ---------------------------------------------------------------------------
extern "C" void kernel_launch(void* const* d_in, const int* in_sizes, int n_in,
                              void* d_out, int out_size, void* d_ws, size_t ws_size,
                              hipStream_t stream) {
    const int*   words     = (const int*)d_in[0];
    const int*   masks     = (const int*)d_in[1];
    const int*   main_idx  = (const int*)d_in[2];
    const int*   main_mask = (const int*)d_in[3];
    const int*   user_idx  = (const int*)d_in[4];
    const int*   user_mask = (const int*)d_in[5];
    const float* adj       = (const float*)d_in[6];
    const float* emb       = (const float*)d_in[7];
    const float* K_w       = (const float*)d_in[8];
    const float* K_b       = (const float*)d_in[9];
    const float* Q_w       = (const float*)d_in[10];
    const float* Q_b       = (const float*)d_in[11];

    float* out = (float*)d_out;
    char*  ws8 = (char*)d_ws;

    ushort* gbf     = (ushort*)(ws8 + WSB_GBF);
    ushort* gT      = (ushort*)(ws8 + WSB_GT);
    ushort* densebf = (ushort*)(ws8 + WSB_DENSEBF);
    ushort* hbf     = (ushort*)(ws8 + WSB_HBF);
    ushort* KwbT    = (ushort*)(ws8 + WSB_KWT);
    ushort* QwbT    = (ushort*)(ws8 + WSB_QWT);
    ushort* Mt      = (ushort*)(ws8 + WSB_MT);
    float*  partU   = (float*)(ws8 + WSB_PARTU);
    float*  partM   = (float*)(ws8 + WSB_PARTM);
    double* kbar    = (double*)(ws8 + WSB_KBAR);
    double* qbar    = (double*)(ws8 + WSB_QBAR);
    double* u       = (double*)(ws8 + WSB_U);
    double* v       = (double*)(ws8 + WSB_V);
    double* va      = (double*)(ws8 + WSB_VA);
    double* vb      = (double*)(ws8 + WSB_VB);
    double* consts  = (double*)(ws8 + WSB_CONSTS);
    float*  qs      = (float*)(ws8 + WSB_QS);
    float*  kq      = (float*)(ws8 + WSB_KQ);
    float*  ga      = (float*)(ws8 + WSB_GA);
    float*  gb      = (float*)(ws8 + WSB_GB);
    float*  colsum  = (float*)(ws8 + WSB_COLSUM);
    int*    flags   = (int*)(ws8 + WSB_FLAGS);
    float*  rowsum  = (float*)(ws8 + WSB_ROWSUM);
    double* uvu     = (double*)(ws8 + WSB_UVU);
    double* uvv     = (double*)(ws8 + WSB_UVV);
    double* uva     = (double*)(ws8 + WSB_UVA);
    double* uvb     = (double*)(ws8 + WSB_UVB);

    float* dense = out + OFF_DENSE;

    // 1: weight row-sums + transposed bf16 converts + colsum zero
    fold1<<<1345, 256, 0, stream>>>(K_w, K_b, Q_w, Q_b, kbar, qbar, KwbT, QwbT, colsum);

    // 2: adj softmax (LDS-staged) + rowsum/colsum  ∥  u/v/a/b fold partials
    adjsm_uv_kernel<<<524, 512, 0, stream>>>(adj, out + OFF_ADJ, colsum, rowsum,
                                             K_w, Q_w, K_b, Q_b, kbar, qbar,
                                             uvu, uvv, uva, uvb);

    // 3: Mt GEMM ∥ u/v/a/b reduce + consts (merged)
    uvmt_kernel<<<76, 256, 0, stream>>>(QwbT, KwbT, Mt, uvu, uvv, uva, uvb,
                                        kbar, qbar, K_b, Q_b, u, v, va, vb, consts);

    // 4: pools (g + s1 merged)
    pool_g_s1<<<Bn * Sn + 640, 192, 0, stream>>>(
        words, masks, main_idx, main_mask, user_idx, user_mask, emb,
        u, v, va, vb, consts, gbf, qs, kq, ga, gb, flags, partM, partU);

    // 5: h GEMM ∥ transpose g ∥ pool stage2 ∥ node mask (merged)
    midh_kernel<<<6992, 256, 0, stream>>>(gbf, Mt, hbf, gT, partM, partU,
                                          out + OFF_MAIN, out + OFF_USER,
                                          rowsum, colsum, out + OFF_MASK);

    // 6: raw scores[b] = h[b] @ g[b]^T
    gemm_mfma<0><<<dim3(8, 4, Bn), 256, 0, stream>>>(
        hbf, gbf, dense, Dn, Dn, Dn, Sn,
        (long long)Sn * Dn, (long long)Sn * Dn, (long long)Sn * Sn);

    // 7: fixup masked rows/cols + bias rank-1 + softmax
    softmax_fix<<<Bn * Sn, 256, 0, stream>>>(dense, flags, qs, kq, ga, gb, consts, densebf);

    // 8: gcn[b] = P[b] @ g[b]
    gemm_mfma<0><<<dim3(12, 4, Bn), 256, 0, stream>>>(
        densebf, gT, out + OFF_GCN, Sn, Sn, Sn, Dn,
        (long long)Sn * Sn, (long long)Dn * Sn, (long long)Sn * Dn);
}

// Round 11
// 142.576 us; speedup vs baseline: 1.2042x; 1.0553x over previous
//
#include <hip/hip_runtime.h>
#include <hip/hip_bf16.h>
#include <math.h>

// Problem sizes (fixed by reference)
static constexpr int Bn = 16, Sn = 512, Wn = 8, Dn = 768;
static constexpr int Mn_ = 2, WMn = 64;
static constexpr int Un = 32, WUn = 16;

#define INF_VAL 1e12f
#define INV_SQRT_D 0.03608439182435161f

// Output float offsets
static constexpr size_t OFF_GCN   = 0;                    // [16,512,768]
static constexpr size_t OFF_MASK  = 6291456;              // [16,512,1]
static constexpr size_t OFF_DENSE = 6299648;              // [16,512,512]
static constexpr size_t OFF_ADJ   = 10493952;             // [16,512,512]
static constexpr size_t OFF_MAIN  = 14688256;             // [16,2,768]
static constexpr size_t OFF_USER  = 14712832;             // [16,768]

// Workspace byte offsets (~61 MB total; ws is ~393 MB)
static constexpr size_t WSB_GBF     = 0;          // bf16 [8192][768]
static constexpr size_t WSB_GT      = 12582912;   // bf16 [16][768][512]
static constexpr size_t WSB_DENSEBF = 25165824;   // bf16 [8192][512]
static constexpr size_t WSB_HBF     = 33554432;   // bf16 [8192][768]
static constexpr size_t WSB_KWT     = 46137344;   // bf16 [768][768]  (K_w^T)
static constexpr size_t WSB_QWT     = 47316992;   // bf16 [768][768]  (Q_w^T)
static constexpr size_t WSB_MT      = 48496640;   // bf16 [768][768]  (M^T)
static constexpr size_t WSB_PARTU   = 49676288;   // f32 [512][768]
static constexpr size_t WSB_PARTM   = 51249152;   // f32 [128][768]
static constexpr size_t WSB_KBAR    = 51642368;   // f64 [768]
static constexpr size_t WSB_QBAR    = 51648512;   // f64 [768]
static constexpr size_t WSB_U       = 51654656;   // f64 [768]
static constexpr size_t WSB_V       = 51660800;   // f64 [768]
static constexpr size_t WSB_VA      = 51666944;   // f64 [768]
static constexpr size_t WSB_VB      = 51673088;   // f64 [768]
static constexpr size_t WSB_CONSTS  = 51679232;   // f64 [4]
static constexpr size_t WSB_QS      = 51679296;   // f32 [8192]
static constexpr size_t WSB_KQ      = 51712064;   // f32 [8192]
static constexpr size_t WSB_GA      = 51744832;   // f32 [8192]
static constexpr size_t WSB_GB      = 51777600;   // f32 [8192]
static constexpr size_t WSB_COLSUM  = 51810368;   // f32 [8192]
static constexpr size_t WSB_FLAGS   = 51843136;   // int [8192]
static constexpr size_t WSB_ROWSUM  = 51875904;   // f32 [8192]
static constexpr size_t WSB_UVU     = 51908672;   // f64 [8][768]
static constexpr size_t WSB_UVV     = 51957824;   // f64 [8][768]
static constexpr size_t WSB_UVA     = 52006976;   // f64 [8][768]
static constexpr size_t WSB_UVB     = 52056128;   // f64 [8][768]
static constexpr size_t WSB_RAWBF   = 52105280;   // bf16 [8192][512] raw scores

typedef __attribute__((ext_vector_type(8))) short short8;
typedef __attribute__((ext_vector_type(4))) float f32x4;

static __device__ __forceinline__ ushort f2bf(float f) {
    union { float f; unsigned u; } v; v.f = f;
    unsigned u = v.u;
    unsigned r = (u + 0x7FFFu + ((u >> 16) & 1u)) >> 16;
    return (ushort)r;
}

static __device__ __forceinline__ float bf2f(unsigned hi16) {
    union { unsigned u; float f; } v; v.u = hi16 << 16; return v.f;
}

static __device__ __forceinline__ void gload16(const void* g, void* lds) {
    __builtin_amdgcn_global_load_lds(
        (const __attribute__((address_space(1))) void*)g,
        (__attribute__((address_space(3))) void*)lds, 16, 0, 0);
}

static __device__ __forceinline__ void fmax4(float4& a, const float4& x) {
    a.x = fmaxf(a.x, x.x); a.y = fmaxf(a.y, x.y);
    a.z = fmaxf(a.z, x.z); a.w = fmaxf(a.w, x.w);
}

// ---------------------------------------------------------------------------
// fold1: blocks 0..191 kbar/qbar row sums; 192..1343 transpose-convert
// K_w->KwbT, Q_w->QwbT (bf16, [i][e]); 1344 colsum zero.
__global__ __launch_bounds__(256)
void fold1(const float* __restrict__ K_w, const float* __restrict__ K_b,
           const float* __restrict__ Q_w, const float* __restrict__ Q_b,
           double* __restrict__ kbar, double* __restrict__ qbar,
           ushort* __restrict__ KwbT, ushort* __restrict__ QwbT,
           float* __restrict__ colsum) {
    int blk = blockIdx.x, t = threadIdx.x;
    if (blk < 192) {
        int wv = t >> 6, lane = t & 63;
        int r = blk * 4 + wv;
        double sk = 0.0, sq = 0.0;
        for (int d = lane; d < Dn; d += 64) {
            sk += (double)K_w[(size_t)r * Dn + d];
            sq += (double)Q_w[(size_t)r * Dn + d];
        }
        #pragma unroll
        for (int off = 32; off > 0; off >>= 1) {
            sk += __shfl_down(sk, off, 64);
            sq += __shfl_down(sq, off, 64);
        }
        if (lane == 0) {
            kbar[r] = -1e12 * sk + (double)K_b[r];
            qbar[r] = -1e12 * sq + (double)Q_b[r];
        }
    } else if (blk < 1344) {
        int tt = blk - 192;                         // 0..1151
        const float* src = (tt < 576) ? K_w : Q_w;
        ushort* dst = (tt < 576) ? KwbT : QwbT;
        int t6 = (tt < 576) ? tt : tt - 576;
        int e0 = (t6 % 24) * 32, i0 = (t6 / 24) * 32;
        __shared__ ushort tile[32][33];
        int tx = t & 31, ty = t >> 5;
        #pragma unroll
        for (int i2 = 0; i2 < 4; ++i2)
            tile[ty + i2 * 8][tx] = f2bf(src[(size_t)(e0 + ty + i2 * 8) * Dn + i0 + tx]);
        __syncthreads();
        #pragma unroll
        for (int i2 = 0; i2 < 4; ++i2)
            dst[(size_t)(i0 + ty + i2 * 8) * Dn + e0 + tx] = tile[tx][ty + i2 * 8];
    } else {
        for (int i = t; i < Bn * Sn; i += 256) colsum[i] = 0.f;
    }
}

// ---------------------------------------------------------------------------
// shared GEMM body (256 threads): 128x64 tile, BK=128, 48 KB LDS
template<int OUT_BF16>
static __device__ __forceinline__
void gemm_device(const ushort* __restrict__ A, const ushort* __restrict__ B,
                 void* __restrict__ Cout, int bx, int by, int bz,
                 int Km, int lda, int ldb, int ldc,
                 long long sA, long long sB, long long sC,
                 ushort* As, ushort* Bs) {
    const ushort* Ab = A + (size_t)bz * sA;
    const ushort* Bb = B + (size_t)bz * sB;
    int i0 = by * 128, j0 = bx * 64;
    int tid = threadIdx.x;
    int lane = tid & 63, wv = tid >> 6;
    int wr = wv >> 1, wc = wv & 1;
    int ln15 = lane & 15, lkg = lane >> 4;
    int r4 = lane >> 4;
    int c16 = lane & 15;

    f32x4 acc[4][2] = {};

    for (int k0 = 0; k0 < Km; k0 += 128) {
        #pragma unroll
        for (int it = 0; it < 8; ++it) {
            int r = it * 16 + wv * 4 + r4;
            int cc = c16 ^ (r & 15);
            ushort* dstA = As + (it * 4096 + wv * 1024) / 2;
            gload16(Ab + (size_t)(i0 + r) * lda + k0 + cc * 8, dstA);
        }
        #pragma unroll
        for (int it = 0; it < 4; ++it) {
            int r = it * 16 + wv * 4 + r4;
            int cc = c16 ^ (r & 15);
            ushort* dstB = Bs + (it * 4096 + wv * 1024) / 2;
            gload16(Bb + (size_t)(j0 + r) * ldb + k0 + cc * 8, dstB);
        }
        __syncthreads();
        #pragma unroll
        for (int kh = 0; kh < 4; ++kh) {
            short8 af[4], bfr[2];
            int kc = kh * 4 + lkg;
            #pragma unroll
            for (int f = 0; f < 4; ++f) {
                int ra = wr * 64 + f * 16 + ln15;
                af[f] = *(const short8*)((const char*)As + ra * 256 + ((kc ^ (ra & 15)) << 4));
            }
            #pragma unroll
            for (int f = 0; f < 2; ++f) {
                int rb = wc * 32 + f * 16 + ln15;
                bfr[f] = *(const short8*)((const char*)Bs + rb * 256 + ((kc ^ (rb & 15)) << 4));
            }
            #pragma unroll
            for (int fa = 0; fa < 4; ++fa)
                #pragma unroll
                for (int fb = 0; fb < 2; ++fb)
                    acc[fa][fb] = __builtin_amdgcn_mfma_f32_16x16x32_bf16(
                        af[fa], bfr[fb], acc[fa][fb], 0, 0, 0);
        }
        __syncthreads();
    }

    #pragma unroll
    for (int fa = 0; fa < 4; ++fa) {
        #pragma unroll
        for (int fb = 0; fb < 2; ++fb) {
            int n = j0 + wc * 32 + fb * 16 + ln15;
            #pragma unroll
            for (int rr = 0; rr < 4; ++rr) {
                int m = i0 + wr * 64 + fa * 16 + lkg * 4 + rr;
                float val = acc[fa][fb][rr];
                if (OUT_BF16) {
                    ((ushort*)Cout)[(size_t)bz * sC + (size_t)m * ldc + n] = f2bf(val);
                } else {
                    ((float*)Cout)[(size_t)bz * sC + (size_t)m * ldc + n] = val;
                }
            }
        }
    }
}

// standalone GEMM kernel
template<int OUT_BF16>
__global__ __launch_bounds__(256)
void gemm_mfma(const ushort* __restrict__ A, const ushort* __restrict__ B,
               void* __restrict__ Cout,
               int Km, int lda, int ldb, int ldc,
               long long sA, long long sB, long long sC) {
    __shared__ ushort As[128 * 128];
    __shared__ ushort Bs[64 * 128];
    gemm_device<OUT_BF16>(A, B, Cout, blockIdx.x, blockIdx.y, blockIdx.z,
                          Km, lda, ldb, ldc, sA, sB, sC, As, Bs);
}

// ---------------------------------------------------------------------------
// Merged (256 thr): blocks 0..23 u/v/a/b fold partials; 24..95 Mt GEMM;
// 96..607 adj softmax (LDS-staged) + rowsum + colsum partials.
__global__ __launch_bounds__(256)
void adjuvmt_kernel(const float* __restrict__ adj, float* __restrict__ adjsm,
                    float* __restrict__ colsum, float* __restrict__ rowsum,
                    const float* __restrict__ K_w, const float* __restrict__ Q_w,
                    const float* __restrict__ K_b, const float* __restrict__ Q_b,
                    const double* __restrict__ kbar, const double* __restrict__ qbar,
                    double* __restrict__ uvu, double* __restrict__ uvv,
                    double* __restrict__ uva, double* __restrict__ uvb,
                    const ushort* __restrict__ QwbT, const ushort* __restrict__ KwbT,
                    ushort* __restrict__ Mt) {
    __shared__ ushort As[128 * 128];   // 32 KB (also adjsm row stage)
    __shared__ ushort Bs[64 * 128];    // 16 KB (also n1s)
    int blk = blockIdx.x;
    int t = threadIdx.x;
    if (blk < 24) {
        int id = blk * 256 + t;        // 0..6143 = 8 chunks x 768 j
        int c = id / 768;
        int j = id - c * 768;
        int e0 = c * 96;
        double su = 0.0, sv = 0.0, sa = 0.0, sb = 0.0;
        for (int e = e0; e < e0 + 96; ++e) {
            double kw = (double)K_w[(size_t)e * Dn + j];
            double qw = (double)Q_w[(size_t)e * Dn + j];
            su += kw * qbar[e];
            sv += qw * kbar[e];
            sa += kw * (double)Q_b[e];
            sb += qw * (double)K_b[e];
        }
        uvu[(size_t)c * Dn + j] = su;
        uvv[(size_t)c * Dn + j] = sv;
        uva[(size_t)c * Dn + j] = sa;
        uvb[(size_t)c * Dn + j] = sb;
        return;
    }
    if (blk < 96) {
        int g = blk - 24;
        gemm_device<1>(QwbT, KwbT, Mt, g % 12, g / 12, 0,
                       Dn, Dn, Dn, Dn, 0, 0, 0, As, Bs);
        return;
    }
    int ab = blk - 96;                 // 0..511
    int b = ab >> 5, rc = ab & 31;
    const float* base = adj + ((size_t)b * Sn + rc * 16) * Sn;
    float* obase = adjsm + ((size_t)b * Sn + rc * 16) * Sn;
    const float EM1 = 0.36787944117144233f;   // exp(-1)
    const float EP1 = 2.718281828459045f;     // exp(+1)
    float (*rows)[512] = (float(*)[512])As;   // 16*512*4 = 32 KB
    float* n1s = (float*)Bs;
    // stage 16 rows (2 cols per thread)
    #pragma unroll
    for (int r = 0; r < 16; ++r) {
        rows[r][t]       = base[(size_t)r * Sn + t];
        rows[r][t + 256] = base[(size_t)r * Sn + t + 256];
    }
    __syncthreads();
    // per-wave rowsums: wave w handles rows 4w..4w+3 (exact integer sums)
    int wv = t >> 6, lane = t & 63;
    #pragma unroll
    for (int rr2 = 0; rr2 < 4; ++rr2) {
        int r = wv * 4 + rr2;
        float s = 0.f;
        #pragma unroll
        for (int c = 0; c < 8; ++c) s += rows[r][lane + c * 64];
        #pragma unroll
        for (int off = 32; off > 0; off >>= 1) s += __shfl_down(s, off, 64);
        if (lane == 0) {
            n1s[r] = s;
            rowsum[(size_t)b * Sn + rc * 16 + r] = s;
        }
    }
    __syncthreads();
    float colacc0 = 0.f, colacc1 = 0.f;
    #pragma unroll
    for (int r = 0; r < 16; ++r) {
        float a0 = rows[r][t], a1 = rows[r][t + 256];
        colacc0 += a0; colacc1 += a1;
        float n1 = n1s[r];
        float e1, e0;
        if (n1 > 0.f) { e1 = 1.f; e0 = EM1; } else { e1 = EP1; e0 = 1.f; }
        float inv = 1.f / (n1 * e1 + (512.f - n1) * e0);
        obase[(size_t)r * Sn + t]       = (a0 == 1.f ? e1 : e0) * inv;
        obase[(size_t)r * Sn + t + 256] = (a1 == 1.f ? e1 : e0) * inv;
    }
    atomicAdd(&colsum[(size_t)b * Sn + t], colacc0);
    atomicAdd(&colsum[(size_t)b * Sn + t + 256], colacc1);
}

// blocks 0..11: reduce u/v/a/b (64 thr); block 12: consts c0..c3
__global__ __launch_bounds__(64)
void uvred_consts(const double* __restrict__ uvu, const double* __restrict__ uvv,
                  const double* __restrict__ uva, const double* __restrict__ uvb,
                  const double* __restrict__ kbar, const double* __restrict__ qbar,
                  const float* __restrict__ K_b, const float* __restrict__ Q_b,
                  double* __restrict__ u, double* __restrict__ v,
                  double* __restrict__ va, double* __restrict__ vb,
                  double* __restrict__ consts) {
    int blk = blockIdx.x;
    int l = threadIdx.x;
    if (blk < 12) {
        int j = blk * 64 + l;
        double su = 0.0, sv = 0.0, sa = 0.0, sb = 0.0;
        #pragma unroll
        for (int c = 0; c < 8; ++c) {
            su += uvu[(size_t)c * Dn + j];
            sv += uvv[(size_t)c * Dn + j];
            sa += uva[(size_t)c * Dn + j];
            sb += uvb[(size_t)c * Dn + j];
        }
        u[j] = su; v[j] = sv; va[j] = sa; vb[j] = sb;
    } else {
        double c0 = 0.0, c1 = 0.0, c2 = 0.0, c3 = 0.0;
        for (int e = l; e < Dn; e += 64) {
            c0 += kbar[e] * (double)Q_b[e];
            c1 += kbar[e] * qbar[e];
            c2 += qbar[e] * (double)K_b[e];
            c3 += (double)K_b[e] * (double)Q_b[e];
        }
        #pragma unroll
        for (int off = 32; off > 0; off >>= 1) {
            c0 += __shfl_down(c0, off, 64);
            c1 += __shfl_down(c1, off, 64);
            c2 += __shfl_down(c2, off, 64);
            c3 += __shfl_down(c3, off, 64);
        }
        if (l == 0) { consts[0] = c0; consts[1] = c1; consts[2] = c2; consts[3] = c3; }
    }
}

// ---------------------------------------------------------------------------
// merged: blocks 0..8191 = g pool (+f64 dots); 8192..8319 main s1; 8320..8831 user s1
__global__ __launch_bounds__(192)
void pool_g_s1(const int* __restrict__ words, const int* __restrict__ masks,
               const int* __restrict__ main_idx, const int* __restrict__ mmask,
               const int* __restrict__ user_idx, const int* __restrict__ umask,
               const float* __restrict__ emb,
               const double* __restrict__ u, const double* __restrict__ v,
               const double* __restrict__ va, const double* __restrict__ vb,
               const double* __restrict__ consts,
               ushort* __restrict__ gbf, float* __restrict__ qs,
               float* __restrict__ kq, float* __restrict__ ga,
               float* __restrict__ gb, int* __restrict__ flags,
               float* __restrict__ partM, float* __restrict__ partU) {
    int blk = blockIdx.x;
    int t = threadIdx.x;
    if (blk >= Bn * Sn) {
        int s1 = blk - Bn * Sn;
        const int *irow, *mrow;
        float* dst;
        if (s1 < 128) {
            int bm = s1 >> 2, ch = s1 & 3;
            irow = main_idx + (size_t)bm * WMn + ch * 16;
            mrow = mmask + (size_t)bm * WMn + ch * 16;
            dst = partM + (size_t)s1 * Dn;
        } else {
            int bu = s1 - 128;
            irow = user_idx + (size_t)bu * WUn;
            mrow = umask + (size_t)bu * WUn;
            dst = partU + (size_t)bu * Dn;
        }
        float4 acc = make_float4(-INF_VAL, -INF_VAL, -INF_VAL, -INF_VAL);
        #pragma unroll
        for (int w = 0; w < 16; ++w) {
            if (mrow[w] != 0) continue;
            float4 x = ((const float4*)(emb + (size_t)irow[w] * Dn))[t];
            fmax4(acc, x);
        }
        ((float4*)dst)[t] = acc;
        return;
    }
    int bs = blk;
    const int* wrow = words + (size_t)bs * Wn;
    const int* mrow = masks + (size_t)bs * Wn;
    float4 acc = make_float4(-INF_VAL, -INF_VAL, -INF_VAL, -INF_VAL);
    int nm = 0;
    #pragma unroll
    for (int w = 0; w < Wn; ++w) {
        int mk = mrow[w];
        nm += (mk != 0);
        if (mk != 0) continue;
        float4 x = ((const float4*)(emb + (size_t)wrow[w] * Dn))[t];
        fmax4(acc, x);
    }
    ushort4 o;
    o.x = f2bf(acc.x); o.y = f2bf(acc.y); o.z = f2bf(acc.z); o.w = f2bf(acc.w);
    ((ushort4*)(gbf + (size_t)bs * Dn))[t] = o;
    int j = t * 4;
    double dv = v[j] * (double)acc.x + v[j+1] * (double)acc.y
              + v[j+2] * (double)acc.z + v[j+3] * (double)acc.w;
    double du = u[j] * (double)acc.x + u[j+1] * (double)acc.y
              + u[j+2] * (double)acc.z + u[j+3] * (double)acc.w;
    double da = va[j] * (double)acc.x + va[j+1] * (double)acc.y
              + va[j+2] * (double)acc.z + va[j+3] * (double)acc.w;
    double db = vb[j] * (double)acc.x + vb[j+1] * (double)acc.y
              + vb[j+2] * (double)acc.z + vb[j+3] * (double)acc.w;
    #pragma unroll
    for (int off = 32; off > 0; off >>= 1) {
        dv += __shfl_down(dv, off, 64);
        du += __shfl_down(du, off, 64);
        da += __shfl_down(da, off, 64);
        db += __shfl_down(db, off, 64);
    }
    __shared__ double rr[12];
    if ((t & 63) == 0) {
        rr[t >> 6] = dv; rr[3 + (t >> 6)] = du;
        rr[6 + (t >> 6)] = da; rr[9 + (t >> 6)] = db;
    }
    __syncthreads();
    if (t == 0) {
        qs[bs] = (float)(rr[0] + rr[1] + rr[2] + consts[0]);
        kq[bs] = (float)(rr[3] + rr[4] + rr[5] + consts[2]);
        ga[bs] = (float)(rr[6] + rr[7] + rr[8]);
        gb[bs] = (float)(rr[9] + rr[10] + rr[11]);
        flags[bs] = (nm == Wn) ? 1 : 0;
    }
}

// ---------------------------------------------------------------------------
// midh: blocks 0..767 = h GEMM (critical path first); 768..6911 transpose;
// 6912..6943 main s2; 6944..6959 user s2; 6960..6991 node mask.
__global__ __launch_bounds__(256)
void midh_kernel(const ushort* __restrict__ gbf, const ushort* __restrict__ Mt,
                 ushort* __restrict__ hbf, ushort* __restrict__ gT,
                 const float* __restrict__ partM, const float* __restrict__ partU,
                 float* __restrict__ outM, float* __restrict__ outU,
                 const float* __restrict__ rowsum, const float* __restrict__ colsum,
                 float* __restrict__ maskout) {
    __shared__ ushort As[128 * 128];
    __shared__ ushort Bs[64 * 128];
    int blk = blockIdx.x;
    int t = threadIdx.x;
    if (blk < 768) {
        gemm_device<1>(gbf, Mt, hbf, blk % 12, blk / 12, 0,
                       Dn, Dn, Dn, Dn, 0, 0, 0, As, Bs);
        return;
    }
    if (blk < 6912) {
        int bb = blk - 768;
        ushort (*tile)[33] = (ushort(*)[33])As;    // reuse GEMM LDS
        int b = bb / 384;
        int rem = bb - b * 384;
        int d0 = (rem % 24) * 32, s0 = (rem / 24) * 32;
        int tx = t & 31, ty = t >> 5;
        #pragma unroll
        for (int i = 0; i < 4; ++i)
            tile[ty + i * 8][tx] = gbf[((size_t)(b * Sn + s0 + ty + i * 8)) * Dn + d0 + tx];
        __syncthreads();
        #pragma unroll
        for (int i = 0; i < 4; ++i)
            gT[((size_t)(b * Dn + d0 + ty + i * 8)) * Sn + s0 + tx] = tile[tx][ty + i * 8];
        return;
    }
    if (blk >= 6960) {
        int i = (blk - 6960) * 256 + t;
        if (i < Bn * Sn)
            maskout[i] = ((rowsum[i] + colsum[i]) == 0.f) ? 1.f : 0.f;
        return;
    }
    if (t >= 192) return;
    float4 acc = make_float4(-INF_VAL, -INF_VAL, -INF_VAL, -INF_VAL);
    float* dst;
    if (blk < 6944) {
        int bm = blk - 6912;
        #pragma unroll
        for (int c = 0; c < 4; ++c) {
            float4 x = ((const float4*)(partM + (size_t)(bm * 4 + c) * Dn))[t];
            fmax4(acc, x);
        }
        dst = outM + (size_t)bm * Dn;
    } else {
        int b = blk - 6944;
        for (int u2 = 0; u2 < Un; ++u2) {
            float4 x = ((const float4*)(partU + (size_t)(b * Un + u2) * Dn))[t];
            fmax4(acc, x);
        }
        dst = outU + (size_t)b * Dn;
    }
    if (acc.x == -INF_VAL) acc.x = 0.f;
    if (acc.y == -INF_VAL) acc.y = 0.f;
    if (acc.z == -INF_VAL) acc.z = 0.f;
    if (acc.w == -INF_VAL) acc.w = 0.f;
    ((float4*)dst)[t] = acc;
}

// ---------------------------------------------------------------------------
// scores fixup + bias-rank1 correction + row softmax. Raw scores read as bf16
// (finite-only entries; masked rows/cols overridden by exact qs/kq path).
// Thread t handles columns 2t, 2t+1 (vectorized loads/stores).
__global__ __launch_bounds__(256)
void softmax_fix(const ushort* __restrict__ raw, const int* __restrict__ flags,
                 const float* __restrict__ qs, const float* __restrict__ kq,
                 const float* __restrict__ ga, const float* __restrict__ gb,
                 const double* __restrict__ consts,
                 float* __restrict__ dense, ushort* __restrict__ densebf) {
    int bs = blockIdx.x;
    int b = bs >> 9;
    int t = threadIdx.x;
    int c0i = 2 * t, c1idx = 2 * t + 1;
    unsigned rpack = ((const unsigned*)(raw + (size_t)bs * 512))[t];
    float r0 = bf2f(rpack & 0xFFFFu);
    float r1 = bf2f(rpack >> 16);
    int f0 = flags[(b << 9) + c0i];
    int f1 = flags[(b << 9) + c1idx];
    bool sm = flags[bs] != 0;
    float x0, x1;
    if (sm) {
        float c1v = (float)consts[1] * INV_SQRT_D;
        x0 = f0 ? c1v : qs[(b << 9) + c0i] * INV_SQRT_D;
        x1 = f1 ? c1v : qs[(b << 9) + c1idx] * INV_SQRT_D;
    } else {
        float kqi = kq[bs] * INV_SQRT_D;
        float corr = ga[bs] + (float)consts[3];
        x0 = f0 ? kqi : (r0 + corr + gb[(b << 9) + c0i]) * INV_SQRT_D;
        x1 = f1 ? kqi : (r1 + corr + gb[(b << 9) + c1idx]) * INV_SQRT_D;
    }
    float m = fmaxf(x0, x1);
    #pragma unroll
    for (int off = 32; off > 0; off >>= 1) m = fmaxf(m, __shfl_down(m, off, 64));
    __shared__ float red[4];
    __shared__ float bmax, bsum;
    if ((t & 63) == 0) red[t >> 6] = m;
    __syncthreads();
    if (t == 0) bmax = fmaxf(fmaxf(red[0], red[1]), fmaxf(red[2], red[3]));
    __syncthreads();
    float mx = bmax;
    float e0 = expf(x0 - mx), e1 = expf(x1 - mx);
    float s = e0 + e1;
    #pragma unroll
    for (int off = 32; off > 0; off >>= 1) s += __shfl_down(s, off, 64);
    if ((t & 63) == 0) red[t >> 6] = s;
    __syncthreads();
    if (t == 0) bsum = red[0] + red[1] + red[2] + red[3];
    __syncthreads();
    float inv = 1.f / bsum;
    float p0 = e0 * inv, p1 = e1 * inv;
    float2 pv; pv.x = p0; pv.y = p1;
    ((float2*)(dense + (size_t)bs * 512))[t] = pv;
    ((unsigned*)(densebf + (size_t)bs * 512))[t] =
        (unsigned)f2bf(p0) | ((unsigned)f2bf(p1) << 16);
}

// ---------------------------------------------------------------------------
extern "C" void kernel_launch(void* const* d_in, const int* in_sizes, int n_in,
                              void* d_out, int out_size, void* d_ws, size_t ws_size,
                              hipStream_t stream) {
    const int*   words     = (const int*)d_in[0];
    const int*   masks     = (const int*)d_in[1];
    const int*   main_idx  = (const int*)d_in[2];
    const int*   main_mask = (const int*)d_in[3];
    const int*   user_idx  = (const int*)d_in[4];
    const int*   user_mask = (const int*)d_in[5];
    const float* adj       = (const float*)d_in[6];
    const float* emb       = (const float*)d_in[7];
    const float* K_w       = (const float*)d_in[8];
    const float* K_b       = (const float*)d_in[9];
    const float* Q_w       = (const float*)d_in[10];
    const float* Q_b       = (const float*)d_in[11];

    float* out = (float*)d_out;
    char*  ws8 = (char*)d_ws;

    ushort* gbf     = (ushort*)(ws8 + WSB_GBF);
    ushort* gT      = (ushort*)(ws8 + WSB_GT);
    ushort* densebf = (ushort*)(ws8 + WSB_DENSEBF);
    ushort* hbf     = (ushort*)(ws8 + WSB_HBF);
    ushort* KwbT    = (ushort*)(ws8 + WSB_KWT);
    ushort* QwbT    = (ushort*)(ws8 + WSB_QWT);
    ushort* Mt      = (ushort*)(ws8 + WSB_MT);
    ushort* rawbf   = (ushort*)(ws8 + WSB_RAWBF);
    float*  partU   = (float*)(ws8 + WSB_PARTU);
    float*  partM   = (float*)(ws8 + WSB_PARTM);
    double* kbar    = (double*)(ws8 + WSB_KBAR);
    double* qbar    = (double*)(ws8 + WSB_QBAR);
    double* u       = (double*)(ws8 + WSB_U);
    double* v       = (double*)(ws8 + WSB_V);
    double* va      = (double*)(ws8 + WSB_VA);
    double* vb      = (double*)(ws8 + WSB_VB);
    double* consts  = (double*)(ws8 + WSB_CONSTS);
    float*  qs      = (float*)(ws8 + WSB_QS);
    float*  kq      = (float*)(ws8 + WSB_KQ);
    float*  ga      = (float*)(ws8 + WSB_GA);
    float*  gb      = (float*)(ws8 + WSB_GB);
    float*  colsum  = (float*)(ws8 + WSB_COLSUM);
    int*    flags   = (int*)(ws8 + WSB_FLAGS);
    float*  rowsum  = (float*)(ws8 + WSB_ROWSUM);
    double* uvu     = (double*)(ws8 + WSB_UVU);
    double* uvv     = (double*)(ws8 + WSB_UVV);
    double* uva     = (double*)(ws8 + WSB_UVA);
    double* uvb     = (double*)(ws8 + WSB_UVB);

    float* dense = out + OFF_DENSE;

    // 1: weight row-sums + transposed bf16 converts + colsum zero
    fold1<<<1345, 256, 0, stream>>>(K_w, K_b, Q_w, Q_b, kbar, qbar, KwbT, QwbT, colsum);

    // 2: u/v/a/b partials ∥ Mt GEMM ∥ adj softmax + rowsum/colsum (merged)
    adjuvmt_kernel<<<608, 256, 0, stream>>>(adj, out + OFF_ADJ, colsum, rowsum,
                                            K_w, Q_w, K_b, Q_b, kbar, qbar,
                                            uvu, uvv, uva, uvb, QwbT, KwbT, Mt);

    // 3: reduce u/v/a/b + consts (tiny)
    uvred_consts<<<13, 64, 0, stream>>>(uvu, uvv, uva, uvb, kbar, qbar, K_b, Q_b,
                                        u, v, va, vb, consts);

    // 4: pools (g + s1 merged)
    pool_g_s1<<<Bn * Sn + 640, 192, 0, stream>>>(
        words, masks, main_idx, main_mask, user_idx, user_mask, emb,
        u, v, va, vb, consts, gbf, qs, kq, ga, gb, flags, partM, partU);

    // 5: h GEMM ∥ transpose g ∥ pool stage2 ∥ node mask (merged)
    midh_kernel<<<6992, 256, 0, stream>>>(gbf, Mt, hbf, gT, partM, partU,
                                          out + OFF_MAIN, out + OFF_USER,
                                          rowsum, colsum, out + OFF_MASK);

    // 6: raw scores[b] = h[b] @ g[b]^T  -> bf16 (finite entries only matter)
    gemm_mfma<1><<<dim3(8, 4, Bn), 256, 0, stream>>>(
        hbf, gbf, rawbf, Dn, Dn, Dn, Sn,
        (long long)Sn * Dn, (long long)Sn * Dn, (long long)Sn * Sn);

    // 7: fixup masked rows/cols + bias rank-1 + softmax (bf16 raw in)
    softmax_fix<<<Bn * Sn, 256, 0, stream>>>(rawbf, flags, qs, kq, ga, gb, consts,
                                             dense, densebf);

    // 8: gcn[b] = P[b] @ g[b]
    gemm_mfma<0><<<dim3(12, 4, Bn), 256, 0, stream>>>(
        densebf, gT, out + OFF_GCN, Sn, Sn, Sn, Dn,
        (long long)Sn * Sn, (long long)Dn * Sn, (long long)Sn * Dn);
}

// Round 12
// 142.285 us; speedup vs baseline: 1.2067x; 1.0020x over previous
//
#include <hip/hip_runtime.h>
#include <hip/hip_bf16.h>
#include <math.h>

// Problem sizes (fixed by reference)
static constexpr int Bn = 16, Sn = 512, Wn = 8, Dn = 768;
static constexpr int Mn_ = 2, WMn = 64;
static constexpr int Un = 32, WUn = 16;

#define INF_VAL 1e12f
#define INV_SQRT_D 0.03608439182435161f

// Output float offsets
static constexpr size_t OFF_GCN   = 0;                    // [16,512,768]
static constexpr size_t OFF_MASK  = 6291456;              // [16,512,1]
static constexpr size_t OFF_DENSE = 6299648;              // [16,512,512]
static constexpr size_t OFF_ADJ   = 10493952;             // [16,512,512]
static constexpr size_t OFF_MAIN  = 14688256;             // [16,2,768]
static constexpr size_t OFF_USER  = 14712832;             // [16,768]

// Workspace byte offsets (~61 MB total; ws is ~393 MB)
static constexpr size_t WSB_GBF     = 0;          // bf16 [8192][768]
static constexpr size_t WSB_GT      = 12582912;   // bf16 [16][768][512]
static constexpr size_t WSB_DENSEBF = 25165824;   // bf16 [8192][512]
static constexpr size_t WSB_HBF     = 33554432;   // bf16 [8192][768]
static constexpr size_t WSB_KWT     = 46137344;   // bf16 [768][768]  (K_w^T)
static constexpr size_t WSB_QWT     = 47316992;   // bf16 [768][768]  (Q_w^T)
static constexpr size_t WSB_MT      = 48496640;   // bf16 [768][768]  (M^T)
static constexpr size_t WSB_PARTU   = 49676288;   // f32 [512][768]
static constexpr size_t WSB_PARTM   = 51249152;   // f32 [128][768]
static constexpr size_t WSB_KBAR    = 51642368;   // f64 [768]
static constexpr size_t WSB_QBAR    = 51648512;   // f64 [768]
static constexpr size_t WSB_U       = 51654656;   // f64 [768]
static constexpr size_t WSB_V       = 51660800;   // f64 [768]
static constexpr size_t WSB_VA      = 51666944;   // f64 [768]
static constexpr size_t WSB_VB      = 51673088;   // f64 [768]
static constexpr size_t WSB_CONSTS  = 51679232;   // f64 [4]
static constexpr size_t WSB_QS      = 51679296;   // f32 [8192]
static constexpr size_t WSB_KQ      = 51712064;   // f32 [8192]
static constexpr size_t WSB_GA      = 51744832;   // f32 [8192]
static constexpr size_t WSB_GB      = 51777600;   // f32 [8192]
static constexpr size_t WSB_COLSUM  = 51810368;   // f32 [8192]
static constexpr size_t WSB_FLAGS   = 51843136;   // int [8192]
static constexpr size_t WSB_ROWSUM  = 51875904;   // f32 [8192]
static constexpr size_t WSB_UVU     = 51908672;   // f64 [8][768]
static constexpr size_t WSB_UVV     = 51957824;   // f64 [8][768]
static constexpr size_t WSB_UVA     = 52006976;   // f64 [8][768]
static constexpr size_t WSB_UVB     = 52056128;   // f64 [8][768]
static constexpr size_t WSB_RAWBF   = 52105280;   // bf16 [8192][512] raw scores

typedef __attribute__((ext_vector_type(8))) short short8;
typedef __attribute__((ext_vector_type(4))) float f32x4;

static __device__ __forceinline__ ushort f2bf(float f) {
    union { float f; unsigned u; } v; v.f = f;
    unsigned u = v.u;
    unsigned r = (u + 0x7FFFu + ((u >> 16) & 1u)) >> 16;
    return (ushort)r;
}

static __device__ __forceinline__ float bf2f(unsigned hi16) {
    union { unsigned u; float f; } v; v.u = hi16 << 16; return v.f;
}

static __device__ __forceinline__ void gload16(const void* g, void* lds) {
    __builtin_amdgcn_global_load_lds(
        (const __attribute__((address_space(1))) void*)g,
        (__attribute__((address_space(3))) void*)lds, 16, 0, 0);
}

static __device__ __forceinline__ void fmax4(float4& a, const float4& x) {
    a.x = fmaxf(a.x, x.x); a.y = fmaxf(a.y, x.y);
    a.z = fmaxf(a.z, x.z); a.w = fmaxf(a.w, x.w);
}

// ---------------------------------------------------------------------------
// fold1: blocks 0..191 kbar/qbar row sums; 192..1343 transpose-convert
// K_w->KwbT, Q_w->QwbT (bf16, [i][e]); 1344 colsum zero.
__global__ __launch_bounds__(256)
void fold1(const float* __restrict__ K_w, const float* __restrict__ K_b,
           const float* __restrict__ Q_w, const float* __restrict__ Q_b,
           double* __restrict__ kbar, double* __restrict__ qbar,
           ushort* __restrict__ KwbT, ushort* __restrict__ QwbT,
           float* __restrict__ colsum) {
    int blk = blockIdx.x, t = threadIdx.x;
    if (blk < 192) {
        int wv = t >> 6, lane = t & 63;
        int r = blk * 4 + wv;
        double sk = 0.0, sq = 0.0;
        for (int d = lane; d < Dn; d += 64) {
            sk += (double)K_w[(size_t)r * Dn + d];
            sq += (double)Q_w[(size_t)r * Dn + d];
        }
        #pragma unroll
        for (int off = 32; off > 0; off >>= 1) {
            sk += __shfl_down(sk, off, 64);
            sq += __shfl_down(sq, off, 64);
        }
        if (lane == 0) {
            kbar[r] = -1e12 * sk + (double)K_b[r];
            qbar[r] = -1e12 * sq + (double)Q_b[r];
        }
    } else if (blk < 1344) {
        int tt = blk - 192;                         // 0..1151
        const float* src = (tt < 576) ? K_w : Q_w;
        ushort* dst = (tt < 576) ? KwbT : QwbT;
        int t6 = (tt < 576) ? tt : tt - 576;
        int e0 = (t6 % 24) * 32, i0 = (t6 / 24) * 32;
        __shared__ ushort tile[32][33];
        int tx = t & 31, ty = t >> 5;
        #pragma unroll
        for (int i2 = 0; i2 < 4; ++i2)
            tile[ty + i2 * 8][tx] = f2bf(src[(size_t)(e0 + ty + i2 * 8) * Dn + i0 + tx]);
        __syncthreads();
        #pragma unroll
        for (int i2 = 0; i2 < 4; ++i2)
            dst[(size_t)(i0 + ty + i2 * 8) * Dn + e0 + tx] = tile[tx][ty + i2 * 8];
    } else {
        for (int i = t; i < Bn * Sn; i += 256) colsum[i] = 0.f;
    }
}

// ---------------------------------------------------------------------------
// shared GEMM body (256 threads): 64x64 tile, BK=128, 32 KB LDS, 5 blocks/CU.
// K-order per output element identical to previous BK=128 versions.
template<int OUT_BF16>
static __device__ __forceinline__
void gemm_device(const ushort* __restrict__ A, const ushort* __restrict__ B,
                 void* __restrict__ Cout, int bx, int by, int bz,
                 int Km, int lda, int ldb, int ldc,
                 long long sA, long long sB, long long sC,
                 ushort* As, ushort* Bs) {
    const ushort* Ab = A + (size_t)bz * sA;
    const ushort* Bb = B + (size_t)bz * sB;
    int i0 = by * 64, j0 = bx * 64;
    int tid = threadIdx.x;
    int lane = tid & 63, wv = tid >> 6;
    int wr = wv >> 1, wc = wv & 1;
    int ln15 = lane & 15, lkg = lane >> 4;
    int r4 = lane >> 4;       // row within 4-row group
    int c16 = lane & 15;      // 16B chunk index

    f32x4 acc[2][2] = {};

    for (int k0 = 0; k0 < Km; k0 += 128) {
        #pragma unroll
        for (int it = 0; it < 4; ++it) {
            int r = it * 16 + wv * 4 + r4;
            int cc = c16 ^ (r & 15);
            ushort* dstA = As + (it * 4096 + wv * 1024) / 2;   // wave-uniform
            gload16(Ab + (size_t)(i0 + r) * lda + k0 + cc * 8, dstA);
        }
        #pragma unroll
        for (int it = 0; it < 4; ++it) {
            int r = it * 16 + wv * 4 + r4;
            int cc = c16 ^ (r & 15);
            ushort* dstB = Bs + (it * 4096 + wv * 1024) / 2;
            gload16(Bb + (size_t)(j0 + r) * ldb + k0 + cc * 8, dstB);
        }
        __syncthreads();
        #pragma unroll
        for (int kh = 0; kh < 4; ++kh) {
            short8 af[2], bfr[2];
            int kc = kh * 4 + lkg;
            #pragma unroll
            for (int f = 0; f < 2; ++f) {
                int ra = wr * 32 + f * 16 + ln15;
                af[f] = *(const short8*)((const char*)As + ra * 256 + ((kc ^ (ra & 15)) << 4));
                int rb = wc * 32 + f * 16 + ln15;
                bfr[f] = *(const short8*)((const char*)Bs + rb * 256 + ((kc ^ (rb & 15)) << 4));
            }
            #pragma unroll
            for (int fa = 0; fa < 2; ++fa)
                #pragma unroll
                for (int fb = 0; fb < 2; ++fb)
                    acc[fa][fb] = __builtin_amdgcn_mfma_f32_16x16x32_bf16(
                        af[fa], bfr[fb], acc[fa][fb], 0, 0, 0);
        }
        __syncthreads();
    }

    #pragma unroll
    for (int fa = 0; fa < 2; ++fa) {
        #pragma unroll
        for (int fb = 0; fb < 2; ++fb) {
            int n = j0 + wc * 32 + fb * 16 + ln15;
            #pragma unroll
            for (int rr = 0; rr < 4; ++rr) {
                int m = i0 + wr * 32 + fa * 16 + lkg * 4 + rr;
                float val = acc[fa][fb][rr];
                if (OUT_BF16) {
                    ((ushort*)Cout)[(size_t)bz * sC + (size_t)m * ldc + n] = f2bf(val);
                } else {
                    ((float*)Cout)[(size_t)bz * sC + (size_t)m * ldc + n] = val;
                }
            }
        }
    }
}

// standalone GEMM kernel
template<int OUT_BF16>
__global__ __launch_bounds__(256)
void gemm_mfma(const ushort* __restrict__ A, const ushort* __restrict__ B,
               void* __restrict__ Cout,
               int Km, int lda, int ldb, int ldc,
               long long sA, long long sB, long long sC) {
    __shared__ ushort As[64 * 128];
    __shared__ ushort Bs[64 * 128];
    gemm_device<OUT_BF16>(A, B, Cout, blockIdx.x, blockIdx.y, blockIdx.z,
                          Km, lda, ldb, ldc, sA, sB, sC, As, Bs);
}

// ---------------------------------------------------------------------------
// Merged (256 thr): blocks 0..23 u/v/a/b fold partials; 24..167 Mt GEMM;
// 168..679 adj softmax (LDS-staged) + rowsum + colsum partials.
__global__ __launch_bounds__(256)
void adjuvmt_kernel(const float* __restrict__ adj, float* __restrict__ adjsm,
                    float* __restrict__ colsum, float* __restrict__ rowsum,
                    const float* __restrict__ K_w, const float* __restrict__ Q_w,
                    const float* __restrict__ K_b, const float* __restrict__ Q_b,
                    const double* __restrict__ kbar, const double* __restrict__ qbar,
                    double* __restrict__ uvu, double* __restrict__ uvv,
                    double* __restrict__ uva, double* __restrict__ uvb,
                    const ushort* __restrict__ QwbT, const ushort* __restrict__ KwbT,
                    ushort* __restrict__ Mt) {
    __shared__ ushort SB[16384];       // 32 KB: GEMM As+Bs, or adjsm row stage
    __shared__ float n1s[16];
    int blk = blockIdx.x;
    int t = threadIdx.x;
    if (blk < 24) {
        int id = blk * 256 + t;        // 0..6143 = 8 chunks x 768 j
        int c = id / 768;
        int j = id - c * 768;
        int e0 = c * 96;
        double su = 0.0, sv = 0.0, sa = 0.0, sb = 0.0;
        for (int e = e0; e < e0 + 96; ++e) {
            double kw = (double)K_w[(size_t)e * Dn + j];
            double qw = (double)Q_w[(size_t)e * Dn + j];
            su += kw * qbar[e];
            sv += qw * kbar[e];
            sa += kw * (double)Q_b[e];
            sb += qw * (double)K_b[e];
        }
        uvu[(size_t)c * Dn + j] = su;
        uvv[(size_t)c * Dn + j] = sv;
        uva[(size_t)c * Dn + j] = sa;
        uvb[(size_t)c * Dn + j] = sb;
        return;
    }
    if (blk < 168) {
        int g = blk - 24;              // 144 blocks: 12x12 tiles
        gemm_device<1>(QwbT, KwbT, Mt, g % 12, g / 12, 0,
                       Dn, Dn, Dn, Dn, 0, 0, 0, SB, SB + 8192);
        return;
    }
    int ab = blk - 168;                // 0..511
    int b = ab >> 5, rc = ab & 31;
    const float* base = adj + ((size_t)b * Sn + rc * 16) * Sn;
    float* obase = adjsm + ((size_t)b * Sn + rc * 16) * Sn;
    const float EM1 = 0.36787944117144233f;   // exp(-1)
    const float EP1 = 2.718281828459045f;     // exp(+1)
    float (*rows)[512] = (float(*)[512])SB;   // 16*512*4 = 32 KB
    // stage 16 rows (2 cols per thread)
    #pragma unroll
    for (int r = 0; r < 16; ++r) {
        rows[r][t]       = base[(size_t)r * Sn + t];
        rows[r][t + 256] = base[(size_t)r * Sn + t + 256];
    }
    __syncthreads();
    // per-wave rowsums: wave w handles rows 4w..4w+3 (exact integer sums)
    int wv = t >> 6, lane = t & 63;
    #pragma unroll
    for (int rr2 = 0; rr2 < 4; ++rr2) {
        int r = wv * 4 + rr2;
        float s = 0.f;
        #pragma unroll
        for (int c = 0; c < 8; ++c) s += rows[r][lane + c * 64];
        #pragma unroll
        for (int off = 32; off > 0; off >>= 1) s += __shfl_down(s, off, 64);
        if (lane == 0) {
            n1s[r] = s;
            rowsum[(size_t)b * Sn + rc * 16 + r] = s;
        }
    }
    __syncthreads();
    float colacc0 = 0.f, colacc1 = 0.f;
    #pragma unroll
    for (int r = 0; r < 16; ++r) {
        float a0 = rows[r][t], a1 = rows[r][t + 256];
        colacc0 += a0; colacc1 += a1;
        float n1 = n1s[r];
        float e1, e0;
        if (n1 > 0.f) { e1 = 1.f; e0 = EM1; } else { e1 = EP1; e0 = 1.f; }
        float inv = 1.f / (n1 * e1 + (512.f - n1) * e0);
        obase[(size_t)r * Sn + t]       = (a0 == 1.f ? e1 : e0) * inv;
        obase[(size_t)r * Sn + t + 256] = (a1 == 1.f ? e1 : e0) * inv;
    }
    atomicAdd(&colsum[(size_t)b * Sn + t], colacc0);
    atomicAdd(&colsum[(size_t)b * Sn + t + 256], colacc1);
}

// blocks 0..11: reduce u/v/a/b (64 thr); block 12: consts c0..c3
__global__ __launch_bounds__(64)
void uvred_consts(const double* __restrict__ uvu, const double* __restrict__ uvv,
                  const double* __restrict__ uva, const double* __restrict__ uvb,
                  const double* __restrict__ kbar, const double* __restrict__ qbar,
                  const float* __restrict__ K_b, const float* __restrict__ Q_b,
                  double* __restrict__ u, double* __restrict__ v,
                  double* __restrict__ va, double* __restrict__ vb,
                  double* __restrict__ consts) {
    int blk = blockIdx.x;
    int l = threadIdx.x;
    if (blk < 12) {
        int j = blk * 64 + l;
        double su = 0.0, sv = 0.0, sa = 0.0, sb = 0.0;
        #pragma unroll
        for (int c = 0; c < 8; ++c) {
            su += uvu[(size_t)c * Dn + j];
            sv += uvv[(size_t)c * Dn + j];
            sa += uva[(size_t)c * Dn + j];
            sb += uvb[(size_t)c * Dn + j];
        }
        u[j] = su; v[j] = sv; va[j] = sa; vb[j] = sb;
    } else {
        double c0 = 0.0, c1 = 0.0, c2 = 0.0, c3 = 0.0;
        for (int e = l; e < Dn; e += 64) {
            c0 += kbar[e] * (double)Q_b[e];
            c1 += kbar[e] * qbar[e];
            c2 += qbar[e] * (double)K_b[e];
            c3 += (double)K_b[e] * (double)Q_b[e];
        }
        #pragma unroll
        for (int off = 32; off > 0; off >>= 1) {
            c0 += __shfl_down(c0, off, 64);
            c1 += __shfl_down(c1, off, 64);
            c2 += __shfl_down(c2, off, 64);
            c3 += __shfl_down(c3, off, 64);
        }
        if (l == 0) { consts[0] = c0; consts[1] = c1; consts[2] = c2; consts[3] = c3; }
    }
}

// ---------------------------------------------------------------------------
// merged: blocks 0..8191 = g pool (+f64 dots); 8192..8319 main s1; 8320..8831 user s1
__global__ __launch_bounds__(192)
void pool_g_s1(const int* __restrict__ words, const int* __restrict__ masks,
               const int* __restrict__ main_idx, const int* __restrict__ mmask,
               const int* __restrict__ user_idx, const int* __restrict__ umask,
               const float* __restrict__ emb,
               const double* __restrict__ u, const double* __restrict__ v,
               const double* __restrict__ va, const double* __restrict__ vb,
               const double* __restrict__ consts,
               ushort* __restrict__ gbf, float* __restrict__ qs,
               float* __restrict__ kq, float* __restrict__ ga,
               float* __restrict__ gb, int* __restrict__ flags,
               float* __restrict__ partM, float* __restrict__ partU) {
    int blk = blockIdx.x;
    int t = threadIdx.x;
    if (blk >= Bn * Sn) {
        int s1 = blk - Bn * Sn;
        const int *irow, *mrow;
        float* dst;
        if (s1 < 128) {
            int bm = s1 >> 2, ch = s1 & 3;
            irow = main_idx + (size_t)bm * WMn + ch * 16;
            mrow = mmask + (size_t)bm * WMn + ch * 16;
            dst = partM + (size_t)s1 * Dn;
        } else {
            int bu = s1 - 128;
            irow = user_idx + (size_t)bu * WUn;
            mrow = umask + (size_t)bu * WUn;
            dst = partU + (size_t)bu * Dn;
        }
        float4 acc = make_float4(-INF_VAL, -INF_VAL, -INF_VAL, -INF_VAL);
        #pragma unroll
        for (int w = 0; w < 16; ++w) {
            if (mrow[w] != 0) continue;
            float4 x = ((const float4*)(emb + (size_t)irow[w] * Dn))[t];
            fmax4(acc, x);
        }
        ((float4*)dst)[t] = acc;
        return;
    }
    int bs = blk;
    const int* wrow = words + (size_t)bs * Wn;
    const int* mrow = masks + (size_t)bs * Wn;
    float4 acc = make_float4(-INF_VAL, -INF_VAL, -INF_VAL, -INF_VAL);
    int nm = 0;
    #pragma unroll
    for (int w = 0; w < Wn; ++w) {
        int mk = mrow[w];
        nm += (mk != 0);
        if (mk != 0) continue;
        float4 x = ((const float4*)(emb + (size_t)wrow[w] * Dn))[t];
        fmax4(acc, x);
    }
    ushort4 o;
    o.x = f2bf(acc.x); o.y = f2bf(acc.y); o.z = f2bf(acc.z); o.w = f2bf(acc.w);
    ((ushort4*)(gbf + (size_t)bs * Dn))[t] = o;
    int j = t * 4;
    double dv = v[j] * (double)acc.x + v[j+1] * (double)acc.y
              + v[j+2] * (double)acc.z + v[j+3] * (double)acc.w;
    double du = u[j] * (double)acc.x + u[j+1] * (double)acc.y
              + u[j+2] * (double)acc.z + u[j+3] * (double)acc.w;
    double da = va[j] * (double)acc.x + va[j+1] * (double)acc.y
              + va[j+2] * (double)acc.z + va[j+3] * (double)acc.w;
    double db = vb[j] * (double)acc.x + vb[j+1] * (double)acc.y
              + vb[j+2] * (double)acc.z + vb[j+3] * (double)acc.w;
    #pragma unroll
    for (int off = 32; off > 0; off >>= 1) {
        dv += __shfl_down(dv, off, 64);
        du += __shfl_down(du, off, 64);
        da += __shfl_down(da, off, 64);
        db += __shfl_down(db, off, 64);
    }
    __shared__ double rr[12];
    if ((t & 63) == 0) {
        rr[t >> 6] = dv; rr[3 + (t >> 6)] = du;
        rr[6 + (t >> 6)] = da; rr[9 + (t >> 6)] = db;
    }
    __syncthreads();
    if (t == 0) {
        qs[bs] = (float)(rr[0] + rr[1] + rr[2] + consts[0]);
        kq[bs] = (float)(rr[3] + rr[4] + rr[5] + consts[2]);
        ga[bs] = (float)(rr[6] + rr[7] + rr[8]);
        gb[bs] = (float)(rr[9] + rr[10] + rr[11]);
        flags[bs] = (nm == Wn) ? 1 : 0;
    }
}

// ---------------------------------------------------------------------------
// midh: blocks 0..1535 = h GEMM (critical path first); 1536..7679 transpose;
// 7680..7711 main s2; 7712..7727 user s2; 7728..7759 node mask.
__global__ __launch_bounds__(256)
void midh_kernel(const ushort* __restrict__ gbf, const ushort* __restrict__ Mt,
                 ushort* __restrict__ hbf, ushort* __restrict__ gT,
                 const float* __restrict__ partM, const float* __restrict__ partU,
                 float* __restrict__ outM, float* __restrict__ outU,
                 const float* __restrict__ rowsum, const float* __restrict__ colsum,
                 float* __restrict__ maskout) {
    __shared__ ushort SB[16384];       // 32 KB
    int blk = blockIdx.x;
    int t = threadIdx.x;
    if (blk < 1536) {
        gemm_device<1>(gbf, Mt, hbf, blk % 12, blk / 12, 0,
                       Dn, Dn, Dn, Dn, 0, 0, 0, SB, SB + 8192);
        return;
    }
    if (blk < 7680) {
        int bb = blk - 1536;
        ushort (*tile)[33] = (ushort(*)[33])SB;    // reuse GEMM LDS
        int b = bb / 384;
        int rem = bb - b * 384;
        int d0 = (rem % 24) * 32, s0 = (rem / 24) * 32;
        int tx = t & 31, ty = t >> 5;
        #pragma unroll
        for (int i = 0; i < 4; ++i)
            tile[ty + i * 8][tx] = gbf[((size_t)(b * Sn + s0 + ty + i * 8)) * Dn + d0 + tx];
        __syncthreads();
        #pragma unroll
        for (int i = 0; i < 4; ++i)
            gT[((size_t)(b * Dn + d0 + ty + i * 8)) * Sn + s0 + tx] = tile[tx][ty + i * 8];
        return;
    }
    if (blk >= 7728) {
        int i = (blk - 7728) * 256 + t;
        if (i < Bn * Sn)
            maskout[i] = ((rowsum[i] + colsum[i]) == 0.f) ? 1.f : 0.f;
        return;
    }
    if (t >= 192) return;
    float4 acc = make_float4(-INF_VAL, -INF_VAL, -INF_VAL, -INF_VAL);
    float* dst;
    if (blk < 7712) {
        int bm = blk - 7680;
        #pragma unroll
        for (int c = 0; c < 4; ++c) {
            float4 x = ((const float4*)(partM + (size_t)(bm * 4 + c) * Dn))[t];
            fmax4(acc, x);
        }
        dst = outM + (size_t)bm * Dn;
    } else {
        int b = blk - 7712;
        for (int u2 = 0; u2 < Un; ++u2) {
            float4 x = ((const float4*)(partU + (size_t)(b * Un + u2) * Dn))[t];
            fmax4(acc, x);
        }
        dst = outU + (size_t)b * Dn;
    }
    if (acc.x == -INF_VAL) acc.x = 0.f;
    if (acc.y == -INF_VAL) acc.y = 0.f;
    if (acc.z == -INF_VAL) acc.z = 0.f;
    if (acc.w == -INF_VAL) acc.w = 0.f;
    ((float4*)dst)[t] = acc;
}

// ---------------------------------------------------------------------------
// scores fixup + bias-rank1 correction + row softmax. Raw scores read as bf16
// (finite-only entries; masked rows/cols overridden by exact qs/kq path).
__global__ __launch_bounds__(256)
void softmax_fix(const ushort* __restrict__ raw, const int* __restrict__ flags,
                 const float* __restrict__ qs, const float* __restrict__ kq,
                 const float* __restrict__ ga, const float* __restrict__ gb,
                 const double* __restrict__ consts,
                 float* __restrict__ dense, ushort* __restrict__ densebf) {
    int bs = blockIdx.x;
    int b = bs >> 9;
    int t = threadIdx.x;
    int c0i = 2 * t, c1idx = 2 * t + 1;
    unsigned rpack = ((const unsigned*)(raw + (size_t)bs * 512))[t];
    float r0 = bf2f(rpack & 0xFFFFu);
    float r1 = bf2f(rpack >> 16);
    int f0 = flags[(b << 9) + c0i];
    int f1 = flags[(b << 9) + c1idx];
    bool sm = flags[bs] != 0;
    float x0, x1;
    if (sm) {
        float c1v = (float)consts[1] * INV_SQRT_D;
        x0 = f0 ? c1v : qs[(b << 9) + c0i] * INV_SQRT_D;
        x1 = f1 ? c1v : qs[(b << 9) + c1idx] * INV_SQRT_D;
    } else {
        float kqi = kq[bs] * INV_SQRT_D;
        float corr = ga[bs] + (float)consts[3];
        x0 = f0 ? kqi : (r0 + corr + gb[(b << 9) + c0i]) * INV_SQRT_D;
        x1 = f1 ? kqi : (r1 + corr + gb[(b << 9) + c1idx]) * INV_SQRT_D;
    }
    float m = fmaxf(x0, x1);
    #pragma unroll
    for (int off = 32; off > 0; off >>= 1) m = fmaxf(m, __shfl_down(m, off, 64));
    __shared__ float red[4];
    __shared__ float bmax, bsum;
    if ((t & 63) == 0) red[t >> 6] = m;
    __syncthreads();
    if (t == 0) bmax = fmaxf(fmaxf(red[0], red[1]), fmaxf(red[2], red[3]));
    __syncthreads();
    float mx = bmax;
    float e0 = expf(x0 - mx), e1 = expf(x1 - mx);
    float s = e0 + e1;
    #pragma unroll
    for (int off = 32; off > 0; off >>= 1) s += __shfl_down(s, off, 64);
    if ((t & 63) == 0) red[t >> 6] = s;
    __syncthreads();
    if (t == 0) bsum = red[0] + red[1] + red[2] + red[3];
    __syncthreads();
    float inv = 1.f / bsum;
    float p0 = e0 * inv, p1 = e1 * inv;
    float2 pv; pv.x = p0; pv.y = p1;
    ((float2*)(dense + (size_t)bs * 512))[t] = pv;
    ((unsigned*)(densebf + (size_t)bs * 512))[t] =
        (unsigned)f2bf(p0) | ((unsigned)f2bf(p1) << 16);
}

// ---------------------------------------------------------------------------
extern "C" void kernel_launch(void* const* d_in, const int* in_sizes, int n_in,
                              void* d_out, int out_size, void* d_ws, size_t ws_size,
                              hipStream_t stream) {
    const int*   words     = (const int*)d_in[0];
    const int*   masks     = (const int*)d_in[1];
    const int*   main_idx  = (const int*)d_in[2];
    const int*   main_mask = (const int*)d_in[3];
    const int*   user_idx  = (const int*)d_in[4];
    const int*   user_mask = (const int*)d_in[5];
    const float* adj       = (const float*)d_in[6];
    const float* emb       = (const float*)d_in[7];
    const float* K_w       = (const float*)d_in[8];
    const float* K_b       = (const float*)d_in[9];
    const float* Q_w       = (const float*)d_in[10];
    const float* Q_b       = (const float*)d_in[11];

    float* out = (float*)d_out;
    char*  ws8 = (char*)d_ws;

    ushort* gbf     = (ushort*)(ws8 + WSB_GBF);
    ushort* gT      = (ushort*)(ws8 + WSB_GT);
    ushort* densebf = (ushort*)(ws8 + WSB_DENSEBF);
    ushort* hbf     = (ushort*)(ws8 + WSB_HBF);
    ushort* KwbT    = (ushort*)(ws8 + WSB_KWT);
    ushort* QwbT    = (ushort*)(ws8 + WSB_QWT);
    ushort* Mt      = (ushort*)(ws8 + WSB_MT);
    ushort* rawbf   = (ushort*)(ws8 + WSB_RAWBF);
    float*  partU   = (float*)(ws8 + WSB_PARTU);
    float*  partM   = (float*)(ws8 + WSB_PARTM);
    double* kbar    = (double*)(ws8 + WSB_KBAR);
    double* qbar    = (double*)(ws8 + WSB_QBAR);
    double* u       = (double*)(ws8 + WSB_U);
    double* v       = (double*)(ws8 + WSB_V);
    double* va      = (double*)(ws8 + WSB_VA);
    double* vb      = (double*)(ws8 + WSB_VB);
    double* consts  = (double*)(ws8 + WSB_CONSTS);
    float*  qs      = (float*)(ws8 + WSB_QS);
    float*  kq      = (float*)(ws8 + WSB_KQ);
    float*  ga      = (float*)(ws8 + WSB_GA);
    float*  gb      = (float*)(ws8 + WSB_GB);
    float*  colsum  = (float*)(ws8 + WSB_COLSUM);
    int*    flags   = (int*)(ws8 + WSB_FLAGS);
    float*  rowsum  = (float*)(ws8 + WSB_ROWSUM);
    double* uvu     = (double*)(ws8 + WSB_UVU);
    double* uvv     = (double*)(ws8 + WSB_UVV);
    double* uva     = (double*)(ws8 + WSB_UVA);
    double* uvb     = (double*)(ws8 + WSB_UVB);

    float* dense = out + OFF_DENSE;

    // 1: weight row-sums + transposed bf16 converts + colsum zero
    fold1<<<1345, 256, 0, stream>>>(K_w, K_b, Q_w, Q_b, kbar, qbar, KwbT, QwbT, colsum);

    // 2: u/v/a/b partials ∥ Mt GEMM (144 blocks) ∥ adj softmax (merged)
    adjuvmt_kernel<<<680, 256, 0, stream>>>(adj, out + OFF_ADJ, colsum, rowsum,
                                            K_w, Q_w, K_b, Q_b, kbar, qbar,
                                            uvu, uvv, uva, uvb, QwbT, KwbT, Mt);

    // 3: reduce u/v/a/b + consts (tiny)
    uvred_consts<<<13, 64, 0, stream>>>(uvu, uvv, uva, uvb, kbar, qbar, K_b, Q_b,
                                        u, v, va, vb, consts);

    // 4: pools (g + s1 merged)
    pool_g_s1<<<Bn * Sn + 640, 192, 0, stream>>>(
        words, masks, main_idx, main_mask, user_idx, user_mask, emb,
        u, v, va, vb, consts, gbf, qs, kq, ga, gb, flags, partM, partU);

    // 5: h GEMM (1536 blocks) ∥ transpose g ∥ pool stage2 ∥ node mask (merged)
    midh_kernel<<<7760, 256, 0, stream>>>(gbf, Mt, hbf, gT, partM, partU,
                                          out + OFF_MAIN, out + OFF_USER,
                                          rowsum, colsum, out + OFF_MASK);

    // 6: raw scores[b] = h[b] @ g[b]^T -> bf16 (1024 blocks, 4/CU)
    gemm_mfma<1><<<dim3(8, 8, Bn), 256, 0, stream>>>(
        hbf, gbf, rawbf, Dn, Dn, Dn, Sn,
        (long long)Sn * Dn, (long long)Sn * Dn, (long long)Sn * Sn);

    // 7: fixup masked rows/cols + bias rank-1 + softmax (bf16 raw in)
    softmax_fix<<<Bn * Sn, 256, 0, stream>>>(rawbf, flags, qs, kq, ga, gb, consts,
                                             dense, densebf);

    // 8: gcn[b] = P[b] @ g[b]  (1536 blocks, 6/CU)
    gemm_mfma<0><<<dim3(12, 8, Bn), 256, 0, stream>>>(
        densebf, gT, out + OFF_GCN, Sn, Sn, Sn, Dn,
        (long long)Sn * Sn, (long long)Dn * Sn, (long long)Sn * Dn);
}